// Round 2
// baseline (2203.319 us; speedup 1.0000x reference)
//
#include <hip/hip_runtime.h>
#include <hip/hip_bf16.h>
#include <stdint.h>

#define SEQ    1024
#define BATCH  64
#define DIN    384
#define HID    384
#define NLAYER 5

constexpr int Ncols = 3 * HID;       // 1152
constexpr int Kdim  = DIN;           // 384
constexpr int NCH   = BATCH * HID;   // 24576 (full-batch channel count)

typedef __attribute__((ext_vector_type(8))) __bf16 bf16x8;
typedef __attribute__((ext_vector_type(4))) float  f32x4;

// ---------- fp32 -> bf16 hi/lo split (hi = RN(x), lo = RN(x - hi)) ----------
__device__ __forceinline__ uint16_t f32_to_bf16_rn(float x) {
  uint32_t u = __float_as_uint(x);
  u += 0x7FFFu + ((u >> 16) & 1u);
  return (uint16_t)(u >> 16);
}
__device__ __forceinline__ float bf16_to_f32(uint16_t h) {
  return __uint_as_float(((uint32_t)h) << 16);
}
__device__ __forceinline__ void split2(float x, uint16_t& hi, uint16_t& lo) {
  uint16_t h = f32_to_bf16_rn(x);
  lo = f32_to_bf16_rn(x - bf16_to_f32(h));
  hi = h;
}

__device__ __forceinline__ void gload_lds16(const void* g, void* l) {
  __builtin_amdgcn_global_load_lds(
      (const __attribute__((address_space(1))) void*)g,
      (__attribute__((address_space(3))) void*)l, 16, 0, 0);
}

// ---------- prep: W (L,K,N) fp32 -> Wt hi/lo (L,N,K) bf16 (transposed) ----------
__global__ void k_prep_w(const float* __restrict__ W, uint16_t* __restrict__ wthi,
                         uint16_t* __restrict__ wtlo) {
  __shared__ float tile[64][65];
  const int n0 = blockIdx.x * 64;
  const int k0 = blockIdx.y * 64;
  const int layer = blockIdx.z;
  const float* Wl = W + (size_t)layer * Kdim * Ncols;
  const int tx = threadIdx.x & 63, ty = threadIdx.x >> 6;  // ty in 0..3
  #pragma unroll
  for (int i = 0; i < 64; i += 4)
    tile[ty + i][tx] = Wl[(size_t)(k0 + ty + i) * Ncols + n0 + tx];
  __syncthreads();
  uint16_t* whl = wthi + (size_t)layer * Ncols * Kdim;
  uint16_t* wll = wtlo + (size_t)layer * Ncols * Kdim;
  #pragma unroll
  for (int i = 0; i < 64; i += 4) {
    const int n = n0 + ty + i, k = k0 + tx;
    uint16_t hi, lo; split2(tile[tx][ty + i], hi, lo);
    whl[(size_t)n * Kdim + k] = hi;
    wll[(size_t)n * Kdim + k] = lo;
  }
}

// ---------- prep: gather batch-group rows of x (fp32) -> Ahi/Alo (bf16, local layout) ----------
__global__ void k_prep_xg(const float* __restrict__ x, uint16_t* __restrict__ ahi,
                          uint16_t* __restrict__ alo, int n4, int lb, int bgRow) {
  int i = blockIdx.x * blockDim.x + threadIdx.x;
  const int stride = gridDim.x * blockDim.x;
  const float4* x4 = (const float4*)x;
  const int bmask = (1 << lb) - 1;
  for (; i < n4; i += stride) {
    const int rl = i / 96;              // 96 = 384/4 float4s per row
    const int k4 = i - rl * 96;
    const int grow = ((rl >> lb) << 6) + bgRow + (rl & bmask);
    float4 v = x4[(size_t)grow * 96 + k4];
    ushort4 hi, lo;
    split2(v.x, hi.x, lo.x); split2(v.y, hi.y, lo.y);
    split2(v.z, hi.z, lo.z); split2(v.w, hi.w, lo.w);
    ((ushort4*)ahi)[i] = hi;
    ((ushort4*)alo)[i] = lo;
  }
}

// ---------- GEMM: (Ahi+Alo)(Whi+Wlo) 3-term split-bf16 MFMA + activation epilogue ----------
// Tile 128x128, BK=64, 4 waves (2x2), each wave 64x64 (4x4 frags of 16x16x32).
// Z region (cols [0,384)) is written to the OUTPUT buffer in global (s*64+b) row layout.
__global__ __launch_bounds__(256, 2) void k_gemm(
    const uint16_t* __restrict__ Ahi, const uint16_t* __restrict__ Alo,
    const uint16_t* __restrict__ Whi, const uint16_t* __restrict__ Wlo,
    const float* __restrict__ bias,
    float* __restrict__ zt,            // global-layout (aliases d_out)
    float* __restrict__ fs, float* __restrict__ osg,   // group-local layout
    int lb, int bgRow)
{
  __shared__ char smem[65536];
  char* sAhi = smem;
  char* sAlo = smem + 16384;
  char* sBhi = smem + 32768;
  char* sBlo = smem + 49152;

  const int tid  = threadIdx.x;
  const int m0   = blockIdx.x * 128;
  const int n0   = blockIdx.y * 128;
  const int wave = tid >> 6, lane = tid & 63;
  const int wm = (wave >> 1) * 64, wn = (wave & 1) * 64;

  f32x4 acc[4][4] = {};

  const int sr   = tid >> 3;  // 0..31
  const int sseg = tid & 7;   // 16B chunk within 128B row

  for (int kt = 0; kt < Kdim / 64; ++kt) {
    const int k0 = kt * 64;
    __syncthreads();
    #pragma unroll
    for (int i = 0; i < 4; ++i) {
      const int r = i * 32 + sr;
      const int segA = sseg ^ (r & 7);                // pre-swizzled global source
      const size_t ea = (size_t)(m0 + r) * Kdim + k0 + segA * 8;
      const size_t eb = (size_t)(n0 + r) * Kdim + k0 + segA * 8;
      const uint32_t loff = (uint32_t)r * 128 + sseg * 16;  // linear LDS dest
      gload_lds16(Ahi + ea, sAhi + loff);
      gload_lds16(Alo + ea, sAlo + loff);
      gload_lds16(Whi + eb, sBhi + loff);
      gload_lds16(Wlo + eb, sBlo + loff);
    }
    __syncthreads();
    #pragma unroll
    for (int ks = 0; ks < 2; ++ks) {
      bf16x8 fAhi[4], fAlo[4], fBhi[4], fBlo[4];
      const int cbase = ks * 4 + (lane >> 4);
      #pragma unroll
      for (int m = 0; m < 4; ++m) {
        const int row = wm + m * 16 + (lane & 15);
        const uint32_t off = (uint32_t)row * 128 + ((cbase ^ (row & 7)) * 16);
        fAhi[m] = *(const bf16x8*)(sAhi + off);
        fAlo[m] = *(const bf16x8*)(sAlo + off);
      }
      #pragma unroll
      for (int n = 0; n < 4; ++n) {
        const int row = wn + n * 16 + (lane & 15);
        const uint32_t off = (uint32_t)row * 128 + ((cbase ^ (row & 7)) * 16);
        fBhi[n] = *(const bf16x8*)(sBhi + off);
        fBlo[n] = *(const bf16x8*)(sBlo + off);
      }
      #pragma unroll
      for (int m = 0; m < 4; ++m)
        #pragma unroll
        for (int n = 0; n < 4; ++n) {
          acc[m][n] = __builtin_amdgcn_mfma_f32_16x16x32_bf16(fAhi[m], fBhi[n], acc[m][n], 0, 0, 0);
          acc[m][n] = __builtin_amdgcn_mfma_f32_16x16x32_bf16(fAhi[m], fBlo[n], acc[m][n], 0, 0, 0);
          acc[m][n] = __builtin_amdgcn_mfma_f32_16x16x32_bf16(fAlo[m], fBhi[n], acc[m][n], 0, 0, 0);
        }
    }
  }

  // epilogue: bias + activation; column region selects tanh vs sigmoid and target array
  const int region = n0 / HID;  // 0:Z 1:F 2:O (block's 128 cols lie in one region)
  const int bmask = (1 << lb) - 1;
  #pragma unroll
  for (int n = 0; n < 4; ++n) {
    const int jg  = n0 + wn + n * 16 + (lane & 15);
    const int jin = jg - region * HID;
    const float bv = bias[jg];
    #pragma unroll
    for (int m = 0; m < 4; ++m) {
      const int rowb = m0 + wm + m * 16 + ((lane >> 4) * 4);
      #pragma unroll
      for (int r = 0; r < 4; ++r) {
        float v = acc[m][n][r] + bv;
        v = fminf(30.f, fmaxf(-30.f, v));
        float res;
        if (region == 0) { const float e = __expf(-2.f * v); res = (1.f - e) / (1.f + e); }
        else             { res = 1.f / (1.f + __expf(-v)); }
        const int rl = rowb + r;
        if (region == 0) {
          const int grow = ((rl >> lb) << 6) + bgRow + (rl & bmask);
          zt[(size_t)grow * HID + jin] = res;
        } else {
          float* outp = (region == 1) ? fs : osg;
          outp[(size_t)rl * HID + jin] = res;
        }
      }
    }
  }
}

// ---------- scan pass 1: per-chunk composites (a = prod(1-f), b = chunk-local scan) ----------
__global__ void k_scan1(const float* __restrict__ zt, const float* __restrict__ fs,
                        float* __restrict__ compA, float* __restrict__ compB,
                        int NCHg, int CHLEN, int zoff)
{
  const int ch = blockIdx.x * blockDim.x + threadIdx.x;
  if (ch >= NCHg) return;
  const int chunk = blockIdx.y;
  float a = 1.f, b = 0.f;
  const size_t zb0 = (size_t)(chunk * CHLEN) * NCH + zoff + ch;
  const size_t fb0 = (size_t)(chunk * CHLEN) * NCHg + ch;
  float z0[8], f0[8], z1[8], f1[8];
  #pragma unroll
  for (int u = 0; u < 8; ++u) { z0[u] = zt[zb0 + (size_t)u * NCH]; f0[u] = fs[fb0 + (size_t)u * NCHg]; }
  for (int sb = 0; sb < CHLEN; sb += 16) {
    const size_t zb = zb0 + (size_t)sb * NCH;
    const size_t fb = fb0 + (size_t)sb * NCHg;
    #pragma unroll
    for (int u = 0; u < 8; ++u) { z1[u] = zt[zb + (size_t)(u + 8) * NCH]; f1[u] = fs[fb + (size_t)(u + 8) * NCHg]; }
    #pragma unroll
    for (int u = 0; u < 8; ++u) { const float fv = f0[u], av = 1.f - fv; b = av * b + fv * z0[u]; a *= av; }
    if (sb + 16 < CHLEN) {
      #pragma unroll
      for (int u = 0; u < 8; ++u) { z0[u] = zt[zb + (size_t)(u + 16) * NCH]; f0[u] = fs[fb + (size_t)(u + 16) * NCHg]; }
    }
    #pragma unroll
    for (int u = 0; u < 8; ++u) { const float fv = f1[u], av = 1.f - fv; b = av * b + fv * z1[u]; a *= av; }
  }
  compA[chunk * NCHg + ch] = a;
  compB[chunk * NCHg + ch] = b;
}

// ---------- scan pass 2: fold prefix, apply recurrence, write h ----------
template<int WM>  // 0: write Ahi/Alo bf16 (next layer input)  1: write fp32 out
__global__ void k_scan2(const float* __restrict__ zt, const float* __restrict__ fs,
                        const float* __restrict__ os,
                        const float* __restrict__ compA, const float* __restrict__ compB,
                        uint16_t* __restrict__ ahi, uint16_t* __restrict__ alo,
                        float* __restrict__ out,
                        int NCHg, int CHLEN, int zoff)
{
  const int ch = blockIdx.x * blockDim.x + threadIdx.x;
  if (ch >= NCHg) return;
  const int chunk = blockIdx.y;
  float c = 0.f;
  for (int q = 0; q < chunk; ++q)
    c = compB[q * NCHg + ch] + compA[q * NCHg + ch] * c;

  const size_t zb0 = (size_t)(chunk * CHLEN) * NCH + zoff + ch;
  const size_t fb0 = (size_t)(chunk * CHLEN) * NCHg + ch;
  float z0[8], f0[8], o0[8], z1[8], f1[8], o1[8];
  #pragma unroll
  for (int u = 0; u < 8; ++u) {
    z0[u] = zt[zb0 + (size_t)u * NCH];
    f0[u] = fs[fb0 + (size_t)u * NCHg];
    o0[u] = os[fb0 + (size_t)u * NCHg];
  }
  for (int sb = 0; sb < CHLEN; sb += 16) {
    const size_t zb = zb0 + (size_t)sb * NCH;
    const size_t fb = fb0 + (size_t)sb * NCHg;
    #pragma unroll
    for (int u = 0; u < 8; ++u) {
      z1[u] = zt[zb + (size_t)(u + 8) * NCH];
      f1[u] = fs[fb + (size_t)(u + 8) * NCHg];
      o1[u] = os[fb + (size_t)(u + 8) * NCHg];
    }
    #pragma unroll
    for (int u = 0; u < 8; ++u) {
      const float fv = f0[u];
      c = fv * z0[u] + (1.f - fv) * c;
      const float h = o0[u] * c;
      if (WM == 0) { uint16_t hi, lo; split2(h, hi, lo);
        ahi[fb + (size_t)u * NCHg] = hi; alo[fb + (size_t)u * NCHg] = lo; }
      else out[zb + (size_t)u * NCH] = h;
    }
    if (sb + 16 < CHLEN) {
      #pragma unroll
      for (int u = 0; u < 8; ++u) {
        z0[u] = zt[zb + (size_t)(u + 16) * NCH];
        f0[u] = fs[fb + (size_t)(u + 16) * NCHg];
        o0[u] = os[fb + (size_t)(u + 16) * NCHg];
      }
    }
    #pragma unroll
    for (int u = 0; u < 8; ++u) {
      const float fv = f1[u];
      c = fv * z1[u] + (1.f - fv) * c;
      const float h = o1[u] * c;
      if (WM == 0) { uint16_t hi, lo; split2(h, hi, lo);
        ahi[fb + (size_t)(u + 8) * NCHg] = hi; alo[fb + (size_t)(u + 8) * NCHg] = lo; }
      else out[zb + (size_t)(u + 8) * NCH] = h;
    }
  }
}

extern "C" void kernel_launch(void* const* d_in, const int* in_sizes, int n_in,
                              void* d_out, int out_size, void* d_ws, size_t ws_size,
                              hipStream_t stream) {
  const float* x  = (const float*)d_in[0];
  const float* Ws = (const float*)d_in[1];
  const float* bs = (const float*)d_in[2];
  float* out = (float*)d_out;

  // ---- pick smallest batch-group count G whose workspace footprint fits ws_size ----
  int G = 64, lb = 0;
  for (int g = 1; g <= 64; g *= 2) {
    const int Bg_ = BATCH / g;
    const size_t MG_ = (size_t)SEQ * Bg_;
    const int NCHg_ = Bg_ * HID;
    const int NCHUNK_ = (g == 1) ? 8 : (g == 2) ? 16 : (g == 4) ? 32 : 64;
    size_t need = 2 * (size_t)NLAYER * Ncols * Kdim * 2   // Whi+Wlo
                + 2 * MG_ * Kdim * 2                       // Ahi+Alo
                + 2 * MG_ * HID * 4                        // fs+osg
                + 2 * (size_t)NCHUNK_ * NCHg_ * 4          // compA+compB
                + 16 * 256;                                // carve alignment slack
    if (need <= ws_size) { G = g; break; }
  }
  const int Bg = BATCH / G;
  { int t = Bg; lb = 0; while (t > 1) { t >>= 1; ++lb; } }
  const int MG = SEQ * Bg;
  const int NCHg = Bg * HID;
  const int NCHUNK = (G == 1) ? 8 : (G == 2) ? 16 : (G == 4) ? 32 : 64;
  const int CHLEN = SEQ / NCHUNK;

  char* p = (char*)d_ws;
  auto carve = [&](size_t bytes) -> char* {
    char* r = p; p += (bytes + 255) & ~(size_t)255; return r;
  };
  uint16_t* Whi = (uint16_t*)carve((size_t)NLAYER * Ncols * Kdim * 2);
  uint16_t* Wlo = (uint16_t*)carve((size_t)NLAYER * Ncols * Kdim * 2);
  uint16_t* Ahi = (uint16_t*)carve((size_t)MG * Kdim * 2);
  uint16_t* Alo = (uint16_t*)carve((size_t)MG * Kdim * 2);
  float* fsv = (float*)carve((size_t)MG * HID * 4);
  float* osg = (float*)carve((size_t)MG * HID * 4);
  float* cA  = (float*)carve((size_t)NCHUNK * NCHg * 4);
  float* cB  = (float*)carve((size_t)NCHUNK * NCHg * 4);
  float* zt  = out;  // Z lives in the output buffer (global row layout)

  k_prep_w<<<dim3(Ncols / 64, Kdim / 64, NLAYER), 256, 0, stream>>>(Ws, Whi, Wlo);

  const int scanBlocks = (NCHg + 255) / 256;
  for (int bg = 0; bg < G; ++bg) {
    const int bgRow = bg * Bg;
    const int zoff  = bgRow * HID;
    const int n4 = MG * (Kdim / 4);
    k_prep_xg<<<dim3((n4 + 255) / 256 < 4096 ? (n4 + 255) / 256 : 4096), 256, 0, stream>>>(
        x, Ahi, Alo, n4, lb, bgRow);

    for (int layer = 0; layer < NLAYER; ++layer) {
      const uint16_t* wh = Whi + (size_t)layer * Ncols * Kdim;
      const uint16_t* wl = Wlo + (size_t)layer * Ncols * Kdim;
      const float* bias = bs + layer * Ncols;
      k_gemm<<<dim3(MG / 128, Ncols / 128), 256, 0, stream>>>(
          Ahi, Alo, wh, wl, bias, zt, fsv, osg, lb, bgRow);
      k_scan1<<<dim3(scanBlocks, NCHUNK), 256, 0, stream>>>(zt, fsv, cA, cB, NCHg, CHLEN, zoff);
      if (layer < NLAYER - 1)
        k_scan2<0><<<dim3(scanBlocks, NCHUNK), 256, 0, stream>>>(
            zt, fsv, osg, cA, cB, Ahi, Alo, out, NCHg, CHLEN, zoff);
      else
        k_scan2<1><<<dim3(scanBlocks, NCHUNK), 256, 0, stream>>>(
            zt, fsv, osg, cA, cB, Ahi, Alo, out, NCHg, CHLEN, zoff);
    }
  }
}

// Round 3
// 1603.562 us; speedup vs baseline: 1.3740x; 1.3740x over previous
//
#include <hip/hip_runtime.h>
#include <hip/hip_bf16.h>
#include <stdint.h>

#define SEQ    1024
#define BATCH  64
#define DIN    384
#define HID    384
#define NLAYER 5

constexpr int Ncols = 3 * HID;       // 1152
constexpr int Kdim  = DIN;           // 384

typedef __attribute__((ext_vector_type(8))) __bf16 bf16x8;
typedef __attribute__((ext_vector_type(4))) float  f32x4;

// ---------- fp32 -> bf16 hi/lo split (hi = RN(x), lo = RN(x - hi)) ----------
__device__ __forceinline__ uint16_t f32_to_bf16_rn(float x) {
  uint32_t u = __float_as_uint(x);
  u += 0x7FFFu + ((u >> 16) & 1u);
  return (uint16_t)(u >> 16);
}
__device__ __forceinline__ float bf16_to_f32(uint16_t h) {
  return __uint_as_float(((uint32_t)h) << 16);
}
__device__ __forceinline__ void split2(float x, uint16_t& hi, uint16_t& lo) {
  uint16_t h = f32_to_bf16_rn(x);
  lo = f32_to_bf16_rn(x - bf16_to_f32(h));
  hi = h;
}

__device__ __forceinline__ void gload_lds16(const void* g, void* l) {
  __builtin_amdgcn_global_load_lds(
      (const __attribute__((address_space(1))) void*)g,
      (__attribute__((address_space(3))) void*)l, 16, 0, 0);
}

// column remap: new col j' -> original col. j'<768: interleaved (z,f) per h; j'>=768: o.
__device__ __forceinline__ int jmap(int jp) {
  return (jp < 768) ? ((jp >> 1) + (jp & 1) * 384) : jp;
}

// ---------- prep: W (L,K,N) fp32 -> Wt hi/lo (L,N',K) bf16, column-remapped + transposed ----------
__global__ void k_prep_w(const float* __restrict__ W, uint16_t* __restrict__ wthi,
                         uint16_t* __restrict__ wtlo) {
  __shared__ float tile[64][65];
  const int n0 = blockIdx.x * 64;   // new-column tile (regions never mix: 64 | 768)
  const int k0 = blockIdx.y * 64;
  const int layer = blockIdx.z;
  const float* Wl = W + (size_t)layer * Kdim * Ncols;
  const int tx = threadIdx.x & 63, ty = threadIdx.x >> 6;  // ty in 0..3
  const int jsrc = jmap(n0 + tx);
  #pragma unroll
  for (int i = 0; i < 64; i += 4)
    tile[ty + i][tx] = Wl[(size_t)(k0 + ty + i) * Ncols + jsrc];
  __syncthreads();
  uint16_t* whl = wthi + (size_t)layer * Ncols * Kdim;
  uint16_t* wll = wtlo + (size_t)layer * Ncols * Kdim;
  #pragma unroll
  for (int i = 0; i < 64; i += 4) {
    const int n = n0 + ty + i, k = k0 + tx;
    uint16_t hi, lo; split2(tile[tx][ty + i], hi, lo);
    whl[(size_t)n * Kdim + k] = hi;
    wll[(size_t)n * Kdim + k] = lo;
  }
}

// ---------- prep: x (s,b) fp32 -> A (b_local,s) bf16 hi/lo ----------
__global__ void k_prep_xg(const float* __restrict__ x, uint16_t* __restrict__ ahi,
                          uint16_t* __restrict__ alo, int n4, int bgRow) {
  int i = blockIdx.x * blockDim.x + threadIdx.x;
  const int stride = gridDim.x * blockDim.x;
  const float4* x4 = (const float4*)x;
  for (; i < n4; i += stride) {
    const int rl = i / 96;              // 96 float4 per row
    const int k4 = i - rl * 96;
    const int b_local = rl >> 10, s = rl & 1023;
    float4 v = x4[(size_t)(s * 64 + bgRow + b_local) * 96 + k4];
    ushort4 hi, lo;
    split2(v.x, hi.x, lo.x); split2(v.y, hi.y, lo.y);
    split2(v.z, hi.z, lo.z); split2(v.w, hi.w, lo.w);
    ((ushort4*)ahi)[i] = hi;
    ((ushort4*)alo)[i] = lo;
  }
}

// ---------- GEMM + activation + fused per-chunk scan composites ----------
// Rows are (b_local, s): M-tile mt = b_local*8 + chunk covers exactly one time-chunk of one batch.
// zf n-tiles (n0<768): cols 2h+{0,1} -> writes a=1-sig(F), b=sig(F)*tanh(Z) interleaved,
// and the chunk composite (prod a, local scan) to compA/compB. o tiles (n0>=768): sigmoid -> o plane.
__global__ __launch_bounds__(256, 2) void k_gemm(
    const uint16_t* __restrict__ Ahi, const uint16_t* __restrict__ Alo,
    const uint16_t* __restrict__ Whi, const uint16_t* __restrict__ Wlo,
    const float* __restrict__ bias,
    float* __restrict__ zf, float* __restrict__ o,
    float* __restrict__ compA, float* __restrict__ compB,
    int Mtiles, int NCHg)
{
  __shared__ char smem[66560];
  char* sAhi = smem;
  char* sAlo = smem + 16384;
  char* sBhi = smem + 32768;
  char* sBlo = smem + 49152;

  const int tid  = threadIdx.x;
  // XCD-chunked bijective remap (grid = 9*Mtiles, always % 8 == 0); n fastest within chunk.
  const int L = blockIdx.y * 9 + blockIdx.x;
  const int q = (9 * Mtiles) >> 3;
  const int nl = (L & 7) * q + (L >> 3);
  const int mt = nl / 9;
  const int n0 = (nl - mt * 9) * 128;
  const int m0 = mt * 128;

  const int wave = tid >> 6, lane = tid & 63;
  const int wm = (wave >> 1) * 64, wn = (wave & 1) * 64;

  f32x4 acc[4][4] = {};

  const int sr   = tid >> 3;  // 0..31
  const int sseg = tid & 7;   // 16B chunk within 128B row

  for (int kt = 0; kt < Kdim / 64; ++kt) {
    const int k0 = kt * 64;
    __syncthreads();
    #pragma unroll
    for (int i = 0; i < 4; ++i) {
      const int r = i * 32 + sr;
      const int segA = sseg ^ (r & 7);                // pre-swizzled global source
      const size_t ea = (size_t)(m0 + r) * Kdim + k0 + segA * 8;
      const size_t eb = (size_t)(n0 + r) * Kdim + k0 + segA * 8;
      const uint32_t loff = (uint32_t)r * 128 + sseg * 16;  // linear LDS dest
      gload_lds16(Ahi + ea, sAhi + loff);
      gload_lds16(Alo + ea, sAlo + loff);
      gload_lds16(Whi + eb, sBhi + loff);
      gload_lds16(Wlo + eb, sBlo + loff);
    }
    __syncthreads();
    #pragma unroll
    for (int ks = 0; ks < 2; ++ks) {
      bf16x8 fAhi[4], fAlo[4], fBhi[4], fBlo[4];
      const int cbase = ks * 4 + (lane >> 4);
      #pragma unroll
      for (int m = 0; m < 4; ++m) {
        const int row = wm + m * 16 + (lane & 15);
        const uint32_t off = (uint32_t)row * 128 + ((cbase ^ (row & 7)) * 16);
        fAhi[m] = *(const bf16x8*)(sAhi + off);
        fAlo[m] = *(const bf16x8*)(sAlo + off);
      }
      #pragma unroll
      for (int n = 0; n < 4; ++n) {
        const int row = wn + n * 16 + (lane & 15);
        const uint32_t off = (uint32_t)row * 128 + ((cbase ^ (row & 7)) * 16);
        fBhi[n] = *(const bf16x8*)(sBhi + off);
        fBlo[n] = *(const bf16x8*)(sBlo + off);
      }
      #pragma unroll
      for (int m = 0; m < 4; ++m)
        #pragma unroll
        for (int n = 0; n < 4; ++n) {
          acc[m][n] = __builtin_amdgcn_mfma_f32_16x16x32_bf16(fAhi[m], fBhi[n], acc[m][n], 0, 0, 0);
          acc[m][n] = __builtin_amdgcn_mfma_f32_16x16x32_bf16(fAhi[m], fBlo[n], acc[m][n], 0, 0, 0);
          acc[m][n] = __builtin_amdgcn_mfma_f32_16x16x32_bf16(fAlo[m], fBhi[n], acc[m][n], 0, 0, 0);
        }
    }
  }

  if (n0 < 768) {
    // ---- zf region: interleaved (z,f) columns; write a,b + compute chunk composite ----
    float* aLDS = (float*)smem;              // [128][65]
    float* bLDS = (float*)(smem + 33280);
    __syncthreads();                         // staging reads done before LDS reuse
    const int p = lane & 1;                  // 0: z column, 1: f column
    #pragma unroll
    for (int n = 0; n < 4; ++n) {
      const int cl = wn + n * 16 + (lane & 15);     // col within 128
      const int jg = n0 + cl;
      const float bv = bias[(jg >> 1) + (jg & 1) * 384];
      const int hloc = cl >> 1;                     // 0..63
      #pragma unroll
      for (int m = 0; m < 4; ++m) {
        const int tb = wm + m * 16 + ((lane >> 4) * 4);
        #pragma unroll
        for (int r = 0; r < 4; ++r) {
          const int t = tb + r;
          float v = acc[m][n][r] + bv;
          v = fminf(30.f, fmaxf(-30.f, v));
          const float e = __expf(p ? -v : -2.f * v);
          const float s = 1.f / (1.f + e);
          const float res = p ? s : fmaf(2.f, s, -1.f);   // f=sig(v) or z=tanh(v)
          const float other = __shfl_xor(res, 1);
          const float fv = p ? res : other;
          const float zv = p ? other : res;
          const float av = 1.f - fv;
          const float bbv = fv * zv;
          zf[(size_t)(m0 + t) * 768 + jg] = p ? bbv : av;
          if (!p) { aLDS[t * 65 + hloc] = av; bLDS[t * 65 + hloc] = bbv; }
        }
      }
    }
    __syncthreads();
    if (tid < 128) {
      const int h = tid >> 1, half = tid & 1;
      float A = 1.f, B = 0.f;
      const int tb = half * 64;
      for (int s = 0; s < 64; ++s) {
        const float a = aLDS[(tb + s) * 65 + h];
        const float b = bLDS[(tb + s) * 65 + h];
        B = fmaf(a, B, b);
        A *= a;
      }
      const float A2 = __shfl_xor(A, 1);
      const float B2 = __shfl_xor(B, 1);
      if (half == 0) {
        const float Af = A2 * A;
        const float Bf = fmaf(A2, B, B2);
        const int b_local = mt >> 3, chunk = mt & 7;
        const int chg = b_local * 384 + (n0 >> 1) + h;
        compA[chunk * NCHg + chg] = Af;
        compB[chunk * NCHg + chg] = Bf;
      }
    }
  } else {
    // ---- o region: sigmoid -> o plane ----
    #pragma unroll
    for (int n = 0; n < 4; ++n) {
      const int jg = n0 + wn + n * 16 + (lane & 15);
      const float bv = bias[jg];
      #pragma unroll
      for (int m = 0; m < 4; ++m) {
        const int tb = wm + m * 16 + ((lane >> 4) * 4);
        #pragma unroll
        for (int r = 0; r < 4; ++r) {
          float v = acc[m][n][r] + bv;
          v = fminf(30.f, fmaxf(-30.f, v));
          const float s = 1.f / (1.f + __expf(-v));
          o[(size_t)(m0 + tb + r) * 384 + (jg - 768)] = s;
        }
      }
    }
  }
}

// ---------- scan: fold chunk prefix, apply recurrence, write h ----------
template<int WM>  // 0: write Ahi/Alo bf16 (next layer input, (b,s) layout)  1: write fp32 out (s,b)
__global__ void k_scan(const float2* __restrict__ zf2, const float* __restrict__ o,
                       const float* __restrict__ compA, const float* __restrict__ compB,
                       uint16_t* __restrict__ ahi, uint16_t* __restrict__ alo,
                       float* __restrict__ out, int NCHg, int bgRow)
{
  const int ch = blockIdx.x * blockDim.x + threadIdx.x;
  if (ch >= NCHg) return;
  const int chunk = blockIdx.y;
  const int b_local = ch / 384;
  const int h = ch - b_local * 384;
  float c = 0.f;
  for (int q = 0; q < chunk; ++q)
    c = fmaf(compA[q * NCHg + ch], c, compB[q * NCHg + ch]);

  const int r0 = b_local * 1024 + chunk * 128;
  const size_t base = (size_t)r0 * 384 + h;
  float2 ab0[8], ab1[8]; float ov0[8], ov1[8];
  #pragma unroll
  for (int u = 0; u < 8; ++u) {
    ab0[u] = zf2[base + (size_t)u * 384];
    ov0[u] = o[base + (size_t)u * 384];
  }
  for (int t0 = 0; t0 < 128; t0 += 16) {
    const size_t bb = base + (size_t)t0 * 384;
    #pragma unroll
    for (int u = 0; u < 8; ++u) {
      ab1[u] = zf2[bb + (size_t)(u + 8) * 384];
      ov1[u] = o[bb + (size_t)(u + 8) * 384];
    }
    #pragma unroll
    for (int u = 0; u < 8; ++u) {
      c = fmaf(ab0[u].x, c, ab0[u].y);
      const float hv = ov0[u] * c;
      const size_t w = bb + (size_t)u * 384;
      if (WM == 0) { uint16_t hi, lo; split2(hv, hi, lo); ahi[w] = hi; alo[w] = lo; }
      else { const int t = chunk * 128 + t0 + u;
             out[(size_t)(t * 64 + bgRow + b_local) * 384 + h] = hv; }
    }
    if (t0 + 16 < 128) {
      #pragma unroll
      for (int u = 0; u < 8; ++u) {
        ab0[u] = zf2[bb + (size_t)(u + 16) * 384];
        ov0[u] = o[bb + (size_t)(u + 16) * 384];
      }
    }
    #pragma unroll
    for (int u = 0; u < 8; ++u) {
      c = fmaf(ab1[u].x, c, ab1[u].y);
      const float hv = ov1[u] * c;
      const size_t w = bb + (size_t)(u + 8) * 384;
      if (WM == 0) { uint16_t hi, lo; split2(hv, hi, lo); ahi[w] = hi; alo[w] = lo; }
      else { const int t = chunk * 128 + t0 + u + 8;
             out[(size_t)(t * 64 + bgRow + b_local) * 384 + h] = hv; }
    }
  }
}

extern "C" void kernel_launch(void* const* d_in, const int* in_sizes, int n_in,
                              void* d_out, int out_size, void* d_ws, size_t ws_size,
                              hipStream_t stream) {
  const float* x  = (const float*)d_in[0];
  const float* Ws = (const float*)d_in[1];
  const float* bs = (const float*)d_in[2];
  float* out = (float*)d_out;

  // ---- pick smallest batch-group count G whose workspace footprint fits ws_size ----
  const size_t wbytes = (size_t)NLAYER * Ncols * Kdim * 2;   // one bf16 plane of W
  int G = 64;
  for (int g = 1; g <= 64; g *= 2) {
    const int Bg_ = BATCH / g;
    const size_t MG_ = (size_t)SEQ * Bg_;
    size_t need = 2 * wbytes
                + 2 * MG_ * Kdim * 2          // Ahi+Alo
                + MG_ * 768 * 4               // zf (a,b interleaved)
                + MG_ * 384 * 4               // o
                + 2 * (size_t)8 * Bg_ * 384 * 4
                + 16 * 256;
    if (need <= ws_size) { G = g; break; }
  }
  const int Bg = BATCH / G;
  const int MG = SEQ * Bg;
  const int NCHg = Bg * HID;
  const int Mtiles = MG / 128;   // = Bg*8

  char* p = (char*)d_ws;
  auto carve = [&](size_t bytes) -> char* {
    char* r = p; p += (bytes + 255) & ~(size_t)255; return r;
  };
  uint16_t* Whi = (uint16_t*)carve(wbytes);
  uint16_t* Wlo = (uint16_t*)carve(wbytes);
  uint16_t* Ahi = (uint16_t*)carve((size_t)MG * Kdim * 2);
  uint16_t* Alo = (uint16_t*)carve((size_t)MG * Kdim * 2);
  float* zf = (float*)carve((size_t)MG * 768 * 4);
  float* ov = (float*)carve((size_t)MG * 384 * 4);
  float* cA = (float*)carve((size_t)8 * NCHg * 4);
  float* cB = (float*)carve((size_t)8 * NCHg * 4);

  k_prep_w<<<dim3(Ncols / 64, Kdim / 64, NLAYER), 256, 0, stream>>>(Ws, Whi, Wlo);

  const int scanBlocks = (NCHg + 255) / 256;
  for (int bg = 0; bg < G; ++bg) {
    const int bgRow = bg * Bg;
    const int n4 = MG * (Kdim / 4);
    const int pblocks = (n4 + 255) / 256 < 4096 ? (n4 + 255) / 256 : 4096;
    k_prep_xg<<<pblocks, 256, 0, stream>>>(x, Ahi, Alo, n4, bgRow);

    for (int layer = 0; layer < NLAYER; ++layer) {
      const uint16_t* wh = Whi + (size_t)layer * Ncols * Kdim;
      const uint16_t* wl = Wlo + (size_t)layer * Ncols * Kdim;
      const float* bias = bs + layer * Ncols;
      k_gemm<<<dim3(9, Mtiles), 256, 0, stream>>>(
          Ahi, Alo, wh, wl, bias, zf, ov, cA, cB, Mtiles, NCHg);
      if (layer < NLAYER - 1)
        k_scan<0><<<dim3(scanBlocks, 8), 256, 0, stream>>>(
            (const float2*)zf, ov, cA, cB, Ahi, Alo, out, NCHg, bgRow);
      else
        k_scan<1><<<dim3(scanBlocks, 8), 256, 0, stream>>>(
            (const float2*)zf, ov, cA, cB, Ahi, Alo, out, NCHg, bgRow);
    }
  }
}

// Round 4
// 1186.983 us; speedup vs baseline: 1.8562x; 1.3510x over previous
//
#include <hip/hip_runtime.h>
#include <hip/hip_bf16.h>
#include <stdint.h>

#define SEQ    1024
#define BATCH  64
#define DIN    384
#define HID    384
#define NLAYER 5

constexpr int Ncols = 3 * HID;       // 1152
constexpr int Kdim  = DIN;           // 384

typedef __attribute__((ext_vector_type(8))) __bf16 bf16x8;
typedef __attribute__((ext_vector_type(4))) float  f32x4;
typedef unsigned int u32;
typedef uint16_t u16;

// ---------- bf16 helpers ----------
__device__ __forceinline__ u16 f32_to_bf16_rn(float x) {
  u32 u = __float_as_uint(x);
  u += 0x7FFFu + ((u >> 16) & 1u);
  return (u16)(u >> 16);
}
__device__ __forceinline__ float bf16_to_f32(u16 h) {
  return __uint_as_float(((u32)h) << 16);
}
__device__ __forceinline__ float bflo(u32 p) { return __uint_as_float(p << 16); }
__device__ __forceinline__ float bfhi(u32 p) { return __uint_as_float(p & 0xFFFF0000u); }
__device__ __forceinline__ u32 packbf(float a, float b) {
  return (u32)f32_to_bf16_rn(a) | ((u32)f32_to_bf16_rn(b) << 16);
}
__device__ __forceinline__ void split2(float x, u16& hi, u16& lo) {
  u16 h = f32_to_bf16_rn(x);
  lo = f32_to_bf16_rn(x - bf16_to_f32(h));
  hi = h;
}

__device__ __forceinline__ void gload_lds16(const void* g, void* l) {
  __builtin_amdgcn_global_load_lds(
      (const __attribute__((address_space(1))) void*)g,
      (__attribute__((address_space(3))) void*)l, 16, 0, 0);
}

// ---------- prep: W (L,K,N) fp32 -> Wt hi/lo (L,N',K) bf16, column-remapped + transposed ----------
__global__ void k_prep_w(const float* __restrict__ W, u16* __restrict__ wthi,
                         u16* __restrict__ wtlo) {
  __shared__ float tile[64][65];
  const int n0 = blockIdx.x * 64;
  const int k0 = blockIdx.y * 64;
  const int layer = blockIdx.z;
  const float* Wl = W + (size_t)layer * Kdim * Ncols;
  const int tx = threadIdx.x & 63, ty = threadIdx.x >> 6;
  const int jp = n0 + tx;
  const int jsrc = (jp < 768) ? ((jp >> 1) + (jp & 1) * 384) : jp;
  #pragma unroll
  for (int i = 0; i < 64; i += 4)
    tile[ty + i][tx] = Wl[(size_t)(k0 + ty + i) * Ncols + jsrc];
  __syncthreads();
  u16* whl = wthi + (size_t)layer * Ncols * Kdim;
  u16* wll = wtlo + (size_t)layer * Ncols * Kdim;
  #pragma unroll
  for (int i = 0; i < 64; i += 4) {
    const int n = n0 + ty + i, k = k0 + tx;
    u16 hi, lo; split2(tile[tx][ty + i], hi, lo);
    whl[(size_t)n * Kdim + k] = hi;
    wll[(size_t)n * Kdim + k] = lo;
  }
}

// ---------- prep: x (s,b) fp32 -> A (b_local,s) bf16 plane (u32-paired) ----------
__global__ void k_prep_xg(const float* __restrict__ x, u32* __restrict__ ap,
                          int n8, int bgRow) {
  int i = blockIdx.x * blockDim.x + threadIdx.x;
  const int stride = gridDim.x * blockDim.x;
  const float4* x4 = (const float4*)x;
  for (; i < n8; i += stride) {
    const int rl = i / 48;              // row (b_local,s); 48 8-float groups per row
    const int k8 = i - rl * 48;
    const int b_local = rl >> 10, s = rl & 1023;
    const size_t src = (size_t)(s * 64 + bgRow + b_local) * 96 + k8 * 2;
    const float4 v0 = x4[src], v1 = x4[src + 1];
    uint4 o;
    o.x = packbf(v0.x, v0.y); o.y = packbf(v0.z, v0.w);
    o.z = packbf(v1.x, v1.y); o.w = packbf(v1.z, v1.w);
    ((uint4*)ap)[i] = o;
  }
}

// ---------- GEMM (2-term A*(Whi+Wlo)) + activations + in-register chunk composites ----------
// 4 waves, each a 128x32 column strip (M_rep=8, N_rep=2). Rows are (b_local, s):
// M-tile mt = b_local*8 + chunk covers one 128-step time-chunk of one batch row.
__global__ __launch_bounds__(256, 3) void k_gemm(
    const u16* __restrict__ A,
    const u16* __restrict__ Whi, const u16* __restrict__ Wlo,
    const float* __restrict__ bias,
    u32* __restrict__ zf, u32* __restrict__ ov,
    float* __restrict__ compA, float* __restrict__ compB,
    int Mtiles, int NCHg)
{
  __shared__ char smem[49152];
  char* sA  = smem;
  char* sWh = smem + 16384;
  char* sWl = smem + 32768;
  u32* rep = (u32*)smem;               // epilogue overlay [128][68]

  const int tid  = threadIdx.x;
  // XCD-chunked bijective remap (grid = 9*Mtiles, multiple of 8); n fastest within chunk.
  const int L = blockIdx.y * 9 + blockIdx.x;
  const int q = (9 * Mtiles) >> 3;
  const int nl = (L & 7) * q + (L >> 3);
  const int mt = nl / 9;
  const int n0 = (nl - mt * 9) * 128;
  const int m0 = mt * 128;

  const int wave = tid >> 6, lane = tid & 63;
  const int wn = wave * 32;

  f32x4 acc[8][2] = {};

  const int sr   = tid >> 3;
  const int sseg = tid & 7;

  for (int kt = 0; kt < Kdim / 64; ++kt) {
    const int k0 = kt * 64;
    __syncthreads();
    #pragma unroll
    for (int i = 0; i < 4; ++i) {
      const int r = i * 32 + sr;
      const int seg = sseg ^ (r & 7);
      const size_t ea = (size_t)(m0 + r) * Kdim + k0 + seg * 8;
      const size_t eb = (size_t)(n0 + r) * Kdim + k0 + seg * 8;
      const u32 loff = (u32)r * 128 + sseg * 16;
      gload_lds16(A + ea,  sA  + loff);
      gload_lds16(Whi + eb, sWh + loff);
      gload_lds16(Wlo + eb, sWl + loff);
    }
    __syncthreads();
    #pragma unroll
    for (int ks = 0; ks < 2; ++ks) {
      const int cbase = ks * 4 + (lane >> 4);
      bf16x8 fA[8], fh[2], fl[2];
      #pragma unroll
      for (int m = 0; m < 8; ++m) {
        const int row = m * 16 + (lane & 15);
        const u32 off = (u32)row * 128 + ((cbase ^ (row & 7)) * 16);
        fA[m] = *(const bf16x8*)(sA + off);
      }
      #pragma unroll
      for (int n = 0; n < 2; ++n) {
        const int row = wn + n * 16 + (lane & 15);
        const u32 off = (u32)row * 128 + ((cbase ^ (row & 7)) * 16);
        fh[n] = *(const bf16x8*)(sWh + off);
        fl[n] = *(const bf16x8*)(sWl + off);
      }
      #pragma unroll
      for (int m = 0; m < 8; ++m)
        #pragma unroll
        for (int n = 0; n < 2; ++n) {
          acc[m][n] = __builtin_amdgcn_mfma_f32_16x16x32_bf16(fA[m], fh[n], acc[m][n], 0, 0, 0);
          acc[m][n] = __builtin_amdgcn_mfma_f32_16x16x32_bf16(fA[m], fl[n], acc[m][n], 0, 0, 0);
        }
    }
  }
  __syncthreads();   // all LDS reads done; staging area reusable

  const int p = lane & 1;
  const int qv = lane >> 4;

  if (n0 < 768) {
    // ---- zf region: a = 1-sig(F), b = sig(F)*tanh(Z); pack bf16; chunk composite in-register ----
    #pragma unroll
    for (int n = 0; n < 2; ++n) {
      const int cl = wn + n * 16 + (lane & 15);
      const int jg = n0 + cl;
      const float bv = bias[(jg >> 1) + (jg & 1) * 384];
      const int hloc = cl >> 1;
      float Arun = 1.f, Brun = 0.f;
      #pragma unroll
      for (int m = 0; m < 8; ++m) {
        float Aseg = 1.f, Bseg = 0.f;
        #pragma unroll
        for (int r = 0; r < 4; ++r) {
          float v = acc[m][n][r] + bv;
          v = fminf(30.f, fmaxf(-30.f, v));
          const float e = __expf(p ? -v : -2.f * v);
          const float s = 1.f / (1.f + e);
          const float res = p ? s : fmaf(2.f, s, -1.f);
          const float other = __shfl_xor(res, 1);
          const float fv = p ? res : other;
          const float zv = p ? other : res;
          const float av = 1.f - fv;
          const float bb = fv * zv;
          if (!p) rep[(m * 16 + qv * 4 + r) * 68 + hloc] = packbf(av, bb);
          Bseg = fmaf(av, Bseg, bb);
          Aseg *= av;
        }
        // combine q-segments (rows m*16 + q*4 + r): butterfly ordered by q bits
        {
          const float Ao = __shfl_xor(Aseg, 16), Bo = __shfl_xor(Bseg, 16);
          const bool late = qv & 1;
          const float Ae = late ? Ao : Aseg, Be = late ? Bo : Bseg;
          const float Al = late ? Aseg : Ao, Bl = late ? Bseg : Bo;
          Aseg = Al * Ae; Bseg = fmaf(Al, Be, Bl);
        }
        {
          const float Ao = __shfl_xor(Aseg, 32), Bo = __shfl_xor(Bseg, 32);
          const bool late = (qv >> 1) & 1;
          const float Ae = late ? Ao : Aseg, Be = late ? Bo : Bseg;
          const float Al = late ? Aseg : Ao, Bl = late ? Bseg : Bo;
          Aseg = Al * Ae; Bseg = fmaf(Al, Be, Bl);
        }
        Brun = fmaf(Aseg, Brun, Bseg);
        Arun *= Aseg;
      }
      if (!p && qv == 0) {
        const int b_local = mt >> 3, chunk = mt & 7;
        const int chg = b_local * 384 + (n0 >> 1) + hloc;
        compA[chunk * NCHg + chg] = Arun;
        compB[chunk * NCHg + chg] = Brun;
      }
    }
    __syncthreads();
    const int colBase = n0 >> 1;
    #pragma unroll
    for (int i = 0; i < 8; ++i) {
      const int c = tid + 256 * i;
      const int t = c >> 4;
      const int j = (c & 15) * 4;
      const uint4 v = *(const uint4*)&rep[t * 68 + j];
      *(uint4*)&zf[(size_t)(m0 + t) * 384 + colBase + j] = v;
    }
  } else {
    // ---- o region: sigmoid, pack bf16 pairs ----
    #pragma unroll
    for (int n = 0; n < 2; ++n) {
      const int cl = wn + n * 16 + (lane & 15);
      const int jg = n0 + cl;
      const float bv = bias[jg];
      const int hloc = cl >> 1;
      #pragma unroll
      for (int m = 0; m < 8; ++m)
        #pragma unroll
        for (int r = 0; r < 4; ++r) {
          float v = acc[m][n][r] + bv;
          v = fminf(30.f, fmaxf(-30.f, v));
          const float s = 1.f / (1.f + __expf(-v));
          const float so = __shfl_xor(s, 1);
          if (!p) rep[(m * 16 + qv * 4 + r) * 68 + hloc] =
              (u32)f32_to_bf16_rn(s) | ((u32)f32_to_bf16_rn(so) << 16);
        }
    }
    __syncthreads();
    const int colBase = (n0 - 768) >> 1;
    #pragma unroll
    for (int i = 0; i < 8; ++i) {
      const int c = tid + 256 * i;
      const int t = c >> 4;
      const int j = (c & 15) * 4;
      const uint4 v = *(const uint4*)&rep[t * 68 + j];
      *(uint4*)&ov[(size_t)(m0 + t) * 192 + colBase + j] = v;
    }
  }
}

// ---------- scan: fold chunk prefix, apply recurrence, write h ----------
template<int WM>  // 0: write bf16 A plane (next layer input)  1: write fp32 out (s,b)
__global__ void k_scan(const u32* __restrict__ zfp, const u32* __restrict__ op,
                       const float* __restrict__ compA, const float* __restrict__ compB,
                       u32* __restrict__ anext, float* __restrict__ out,
                       int NCHg, int bgRow)
{
  const int ch = blockIdx.x * blockDim.x + threadIdx.x;
  if (ch >= NCHg) return;
  const int chunk = blockIdx.y;
  const int b_local = ch / 384;
  const int h = ch - b_local * 384;
  float c = 0.f;
  for (int q = 0; q < chunk; ++q)
    c = fmaf(compA[q * NCHg + ch], c, compB[q * NCHg + ch]);

  const int r0 = b_local * 1024 + chunk * 128;
  const size_t zbase = (size_t)r0 * 384 + h;
  const size_t obase = (size_t)r0 * 192 + (h >> 1);
  const int osel = h & 1;

  u32 ab0[8], ab1[8], ow0[8], ow1[8];
  #pragma unroll
  for (int u = 0; u < 8; ++u) {
    ab0[u] = zfp[zbase + (size_t)u * 384];
    ow0[u] = op[obase + (size_t)u * 192];
  }
  for (int t0 = 0; t0 < 128; t0 += 16) {
    const size_t zb = zbase + (size_t)t0 * 384;
    const size_t ob = obase + (size_t)t0 * 192;
    #pragma unroll
    for (int u = 0; u < 8; ++u) {
      ab1[u] = zfp[zb + (size_t)(u + 8) * 384];
      ow1[u] = op[ob + (size_t)(u + 8) * 192];
    }
    #pragma unroll
    for (int u = 0; u < 8; ++u) {
      c = fmaf(bflo(ab0[u]), c, bfhi(ab0[u]));
      const float o = osel ? bfhi(ow0[u]) : bflo(ow0[u]);
      const float hv = o * c;
      const int t = t0 + u;
      if (WM == 0) {
        const u32 me = (u32)f32_to_bf16_rn(hv);
        const u32 nb = (u32)__shfl_xor((int)me, 1);
        if (!osel) anext[(size_t)(r0 + t) * 192 + (h >> 1)] = me | (nb << 16);
      } else {
        out[(size_t)((chunk * 128 + t) * 64 + bgRow + b_local) * 384 + h] = hv;
      }
    }
    if (t0 + 16 < 128) {
      #pragma unroll
      for (int u = 0; u < 8; ++u) {
        ab0[u] = zfp[zb + (size_t)(u + 16) * 384];
        ow0[u] = op[ob + (size_t)(u + 16) * 192];
      }
    }
    #pragma unroll
    for (int u = 0; u < 8; ++u) {
      c = fmaf(bflo(ab1[u]), c, bfhi(ab1[u]));
      const float o = osel ? bfhi(ow1[u]) : bflo(ow1[u]);
      const float hv = o * c;
      const int t = t0 + u + 8;
      if (WM == 0) {
        const u32 me = (u32)f32_to_bf16_rn(hv);
        const u32 nb = (u32)__shfl_xor((int)me, 1);
        if (!osel) anext[(size_t)(r0 + t) * 192 + (h >> 1)] = me | (nb << 16);
      } else {
        out[(size_t)((chunk * 128 + t) * 64 + bgRow + b_local) * 384 + h] = hv;
      }
    }
  }
}

extern "C" void kernel_launch(void* const* d_in, const int* in_sizes, int n_in,
                              void* d_out, int out_size, void* d_ws, size_t ws_size,
                              hipStream_t stream) {
  const float* x  = (const float*)d_in[0];
  const float* Ws = (const float*)d_in[1];
  const float* bs = (const float*)d_in[2];
  float* out = (float*)d_out;

  const size_t wbytes = (size_t)NLAYER * Ncols * Kdim * 2;   // one bf16 plane of W
  int G = 64;
  for (int g = 1; g <= 64; g *= 2) {
    const int Bg_ = BATCH / g;
    const size_t MG_ = (size_t)SEQ * Bg_;
    size_t need = 2 * wbytes
                + MG_ * Kdim * 2              // A plane (bf16)
                + MG_ * 384 * 4               // zf packed u32
                + MG_ * 192 * 4               // o packed u32
                + 2 * (size_t)8 * Bg_ * 384 * 4
                + 16 * 256;
    if (need <= ws_size) { G = g; break; }
  }
  const int Bg = BATCH / G;
  const int MG = SEQ * Bg;
  const int NCHg = Bg * HID;
  const int Mtiles = MG / 128;   // = Bg*8

  char* p = (char*)d_ws;
  auto carve = [&](size_t bytes) -> char* {
    char* r = p; p += (bytes + 255) & ~(size_t)255; return r;
  };
  u16* Whi = (u16*)carve(wbytes);
  u16* Wlo = (u16*)carve(wbytes);
  u32* Ap  = (u32*)carve((size_t)MG * Kdim * 2);
  u32* zf  = (u32*)carve((size_t)MG * 384 * 4);
  u32* ov  = (u32*)carve((size_t)MG * 192 * 4);
  float* cA = (float*)carve((size_t)8 * NCHg * 4);
  float* cB = (float*)carve((size_t)8 * NCHg * 4);

  k_prep_w<<<dim3(Ncols / 64, Kdim / 64, NLAYER), 256, 0, stream>>>(Ws, Whi, Wlo);

  const int scanBlocks = (NCHg + 255) / 256;
  for (int bg = 0; bg < G; ++bg) {
    const int bgRow = bg * Bg;
    const int n8 = MG * (Kdim / 8);
    const int pblocks = (n8 + 255) / 256 < 4096 ? (n8 + 255) / 256 : 4096;
    k_prep_xg<<<pblocks, 256, 0, stream>>>(x, Ap, n8, bgRow);

    for (int layer = 0; layer < NLAYER; ++layer) {
      const u16* wh = Whi + (size_t)layer * Ncols * Kdim;
      const u16* wl = Wlo + (size_t)layer * Ncols * Kdim;
      const float* bias = bs + layer * Ncols;
      k_gemm<<<dim3(9, Mtiles), 256, 0, stream>>>(
          (const u16*)Ap, wh, wl, bias, zf, ov, cA, cB, Mtiles, NCHg);
      if (layer < NLAYER - 1)
        k_scan<0><<<dim3(scanBlocks, 8), 256, 0, stream>>>(
            zf, ov, cA, cB, Ap, out, NCHg, bgRow);
      else
        k_scan<1><<<dim3(scanBlocks, 8), 256, 0, stream>>>(
            zf, ov, cA, cB, Ap, out, NCHg, bgRow);
    }
  }
}

// Round 5
// 942.957 us; speedup vs baseline: 2.3366x; 1.2588x over previous
//
#include <hip/hip_runtime.h>
#include <hip/hip_bf16.h>
#include <stdint.h>

#define SEQ    1024
#define BATCH  64
#define DIN    384
#define HID    384
#define NLAYER 5

constexpr int Ncols = 3 * HID;       // 1152
constexpr int Kdim  = DIN;           // 384

typedef __attribute__((ext_vector_type(8))) __bf16 bf16x8;
typedef __attribute__((ext_vector_type(4))) float  f32x4;
typedef unsigned int u32;
typedef uint16_t u16;

// ---------- bf16 helpers ----------
__device__ __forceinline__ u16 f32_to_bf16_rn(float x) {
  u32 u = __float_as_uint(x);
  u += 0x7FFFu + ((u >> 16) & 1u);
  return (u16)(u >> 16);
}
__device__ __forceinline__ float bf16_to_f32(u16 h) {
  return __uint_as_float(((u32)h) << 16);
}
__device__ __forceinline__ float bflo(u32 p) { return __uint_as_float(p << 16); }
__device__ __forceinline__ float bfhi(u32 p) { return __uint_as_float(p & 0xFFFF0000u); }
__device__ __forceinline__ u32 packbf(float a, float b) {
  return (u32)f32_to_bf16_rn(a) | ((u32)f32_to_bf16_rn(b) << 16);
}
__device__ __forceinline__ void split2(float x, u16& hi, u16& lo) {
  u16 h = f32_to_bf16_rn(x);
  lo = f32_to_bf16_rn(x - bf16_to_f32(h));
  hi = h;
}

__device__ __forceinline__ void gload_lds16(const void* g, void* l) {
  __builtin_amdgcn_global_load_lds(
      (const __attribute__((address_space(1))) void*)g,
      (__attribute__((address_space(3))) void*)l, 16, 0, 0);
}

// New-column layout:
//   jp < 768 (zf region): groups of 32 = 16 z-cols then 16 f-cols for h = (jp>>5)*16 + (jp&15).
//   jp >= 768 (o region): identity.
__device__ __forceinline__ int jmap(int jp) {
  if (jp >= 768) return jp;
  const int w = jp & 31;
  return ((jp >> 5) << 4) + (w & 15) + ((w & 16) ? 384 : 0);
}

// ---------- prep: W (L,K,N) fp32 -> Wt hi/lo (L,N',K) bf16, column-remapped + transposed ----------
__global__ void k_prep_w(const float* __restrict__ W, u16* __restrict__ wthi,
                         u16* __restrict__ wtlo) {
  __shared__ float tile[64][65];
  const int n0 = blockIdx.x * 64;
  const int k0 = blockIdx.y * 64;
  const int layer = blockIdx.z;
  const float* Wl = W + (size_t)layer * Kdim * Ncols;
  const int tx = threadIdx.x & 63, ty = threadIdx.x >> 6;
  const int jsrc = jmap(n0 + tx);
  #pragma unroll
  for (int i = 0; i < 64; i += 4)
    tile[ty + i][tx] = Wl[(size_t)(k0 + ty + i) * Ncols + jsrc];
  __syncthreads();
  u16* whl = wthi + (size_t)layer * Ncols * Kdim;
  u16* wll = wtlo + (size_t)layer * Ncols * Kdim;
  #pragma unroll
  for (int i = 0; i < 64; i += 4) {
    const int n = n0 + ty + i, k = k0 + tx;
    u16 hi, lo; split2(tile[tx][ty + i], hi, lo);
    whl[(size_t)n * Kdim + k] = hi;
    wll[(size_t)n * Kdim + k] = lo;
  }
}

// ---------- prep: x (s,b) fp32 -> A (b_local,s) bf16 plane (u32-paired) ----------
__global__ void k_prep_xg(const float* __restrict__ x, u32* __restrict__ ap,
                          int n8, int bgRow) {
  int i = blockIdx.x * blockDim.x + threadIdx.x;
  const int stride = gridDim.x * blockDim.x;
  const float4* x4 = (const float4*)x;
  for (; i < n8; i += stride) {
    const int rl = i / 48;              // row (b_local,s); 48 8-float groups per row
    const int k8 = i - rl * 48;
    const int b_local = rl >> 10, s = rl & 1023;
    const size_t src = (size_t)(s * 64 + bgRow + b_local) * 96 + k8 * 2;
    const float4 v0 = x4[src], v1 = x4[src + 1];
    uint4 o;
    o.x = packbf(v0.x, v0.y); o.y = packbf(v0.z, v0.w);
    o.z = packbf(v1.x, v1.y); o.w = packbf(v1.z, v1.w);
    ((uint4*)ap)[i] = o;
  }
}

// ---------- GEMM (2-term A*(Whi+Wlo)) + activations + in-register chunk composites ----------
// 4 waves, each a 128x32 column strip (M_rep=8, N_rep=2). With the jmap column layout a
// wave's frag n=0 = Z-pre and n=1 = F-pre for the SAME 16 h (zf tiles), or o[h], o[h+16]
// (o tiles) -> all activation pairing is lane-local, zero data shuffles.
__global__ __launch_bounds__(256, 3) void k_gemm(
    const u16* __restrict__ A,
    const u16* __restrict__ Whi, const u16* __restrict__ Wlo,
    const float* __restrict__ bias,
    u32* __restrict__ zf, u32* __restrict__ ov,
    float* __restrict__ compA, float* __restrict__ compB,
    int Mtiles, int NCHg)
{
  __shared__ char smem[49152];
  char* sA  = smem;
  char* sWh = smem + 16384;
  char* sWl = smem + 32768;

  const int tid  = threadIdx.x;
  // XCD-chunked bijective remap (grid = 9*Mtiles, multiple of 8); n fastest within chunk.
  const int L = blockIdx.y * 9 + blockIdx.x;
  const int q = (9 * Mtiles) >> 3;
  const int nl = (L & 7) * q + (L >> 3);
  const int mt = nl / 9;
  const int n0 = (nl - mt * 9) * 128;
  const int m0 = mt * 128;

  const int wave = tid >> 6, lane = tid & 63;

  f32x4 acc[8][2] = {};

  const int sr   = tid >> 3;
  const int sseg = tid & 7;

  for (int kt = 0; kt < Kdim / 64; ++kt) {
    const int k0 = kt * 64;
    __syncthreads();
    #pragma unroll
    for (int i = 0; i < 4; ++i) {
      const int r = i * 32 + sr;
      const int seg = sseg ^ (r & 7);
      const size_t ea = (size_t)(m0 + r) * Kdim + k0 + seg * 8;
      const size_t eb = (size_t)(n0 + r) * Kdim + k0 + seg * 8;
      const u32 loff = (u32)r * 128 + sseg * 16;
      gload_lds16(A + ea,   sA  + loff);
      gload_lds16(Whi + eb, sWh + loff);
      gload_lds16(Wlo + eb, sWl + loff);
    }
    __syncthreads();
    #pragma unroll
    for (int ks = 0; ks < 2; ++ks) {
      const int cbase = ks * 4 + (lane >> 4);
      bf16x8 fA[8], fh[2], fl[2];
      #pragma unroll
      for (int m = 0; m < 8; ++m) {
        const int row = m * 16 + (lane & 15);
        const u32 off = (u32)row * 128 + ((cbase ^ (row & 7)) * 16);
        fA[m] = *(const bf16x8*)(sA + off);
      }
      #pragma unroll
      for (int n = 0; n < 2; ++n) {
        const int row = wave * 32 + n * 16 + (lane & 15);
        const u32 off = (u32)row * 128 + ((cbase ^ (row & 7)) * 16);
        fh[n] = *(const bf16x8*)(sWh + off);
        fl[n] = *(const bf16x8*)(sWl + off);
      }
      #pragma unroll
      for (int m = 0; m < 8; ++m)
        #pragma unroll
        for (int n = 0; n < 2; ++n) {
          acc[m][n] = __builtin_amdgcn_mfma_f32_16x16x32_bf16(fA[m], fh[n], acc[m][n], 0, 0, 0);
          acc[m][n] = __builtin_amdgcn_mfma_f32_16x16x32_bf16(fA[m], fl[n], acc[m][n], 0, 0, 0);
        }
    }
  }

  const int qv = lane >> 4;
  const int ln = lane & 15;

  if (n0 < 768) {
    // ---- zf: z = acc[m][0], f = acc[m][1] for column hcol; all lane-local ----
    const int hcol = (n0 >> 1) + wave * 16 + ln;
    const float bz = bias[hcol];
    const float bf = bias[384 + hcol];
    float Arun = 1.f, Brun = 0.f;
    #pragma unroll
    for (int m = 0; m < 8; ++m) {
      float Aseg = 1.f, Bseg = 0.f;
      #pragma unroll
      for (int r = 0; r < 4; ++r) {
        float vz = acc[m][0][r] + bz;
        float vf = acc[m][1][r] + bf;
        vz = fminf(30.f, fmaxf(-30.f, vz));
        vf = fminf(30.f, fmaxf(-30.f, vf));
        const float sz = 1.f / (1.f + __expf(-2.f * vz));
        const float z  = fmaf(2.f, sz, -1.f);           // tanh
        const float f  = 1.f / (1.f + __expf(-vf));     // sigmoid
        const float av = 1.f - f;
        const float bb = f * z;
        const int row = m * 16 + qv * 4 + r;
        zf[(size_t)(m0 + row) * 384 + hcol] = packbf(av, bb);
        Bseg = fmaf(av, Bseg, bb);
        Aseg *= av;
      }
      // merge the 4 qv-owned row segments (rows qv*4+r within the 16-row fragment)
      {
        const float Ao = __shfl_xor(Aseg, 16), Bo = __shfl_xor(Bseg, 16);
        const bool late = qv & 1;
        const float Ae = late ? Ao : Aseg, Be = late ? Bo : Bseg;
        const float Al = late ? Aseg : Ao, Bl = late ? Bseg : Bo;
        Aseg = Al * Ae; Bseg = fmaf(Al, Be, Bl);
      }
      {
        const float Ao = __shfl_xor(Aseg, 32), Bo = __shfl_xor(Bseg, 32);
        const bool late = (qv >> 1) & 1;
        const float Ae = late ? Ao : Aseg, Be = late ? Bo : Bseg;
        const float Al = late ? Aseg : Ao, Bl = late ? Bseg : Bo;
        Aseg = Al * Ae; Bseg = fmaf(Al, Be, Bl);
      }
      Brun = fmaf(Aseg, Brun, Bseg);
      Arun *= Aseg;
    }
    if (qv == 0) {
      const int b_local = mt >> 3, chunk = mt & 7;
      const int chg = b_local * 384 + hcol;
      compA[chunk * NCHg + chg] = Arun;
      compB[chunk * NCHg + chg] = Brun;
    }
  } else {
    // ---- o: pair (h, h+16) lane-locally, pack u32, scattered direct stores ----
    const int hb = (n0 - 768) + wave * 32 + ln;     // pair base (h&31 < 16)
    const float b0 = bias[768 + hb];
    const float b1 = bias[768 + hb + 16];
    const int pos = ((hb >> 5) << 4) + (hb & 15);
    #pragma unroll
    for (int m = 0; m < 8; ++m)
      #pragma unroll
      for (int r = 0; r < 4; ++r) {
        float v0 = acc[m][0][r] + b0;
        float v1 = acc[m][1][r] + b1;
        v0 = fminf(30.f, fmaxf(-30.f, v0));
        v1 = fminf(30.f, fmaxf(-30.f, v1));
        const float s0 = 1.f / (1.f + __expf(-v0));
        const float s1 = 1.f / (1.f + __expf(-v1));
        const int row = m * 16 + qv * 4 + r;
        ov[(size_t)(m0 + row) * 192 + pos] = packbf(s0, s1);
      }
  }
}

// ---------- scan: fold chunk prefix, apply recurrence, write h ----------
template<int WM>  // 0: write bf16 A plane (next layer input)  1: write fp32 out (s,b)
__global__ void k_scan(const u32* __restrict__ zfp, const u32* __restrict__ op,
                       const float* __restrict__ compA, const float* __restrict__ compB,
                       u32* __restrict__ anext, float* __restrict__ out,
                       int NCHg, int bgRow)
{
  const int ch = blockIdx.x * blockDim.x + threadIdx.x;
  if (ch >= NCHg) return;
  const int chunk = blockIdx.y;
  const int b_local = ch / 384;
  const int h = ch - b_local * 384;
  float c = 0.f;
  for (int q = 0; q < chunk; ++q)
    c = fmaf(compA[q * NCHg + ch], c, compB[q * NCHg + ch]);

  const int r0 = b_local * 1024 + chunk * 128;
  const size_t zbase = (size_t)r0 * 384 + h;
  const size_t obase = (size_t)r0 * 192 + (((h >> 5) << 4) + (h & 15));
  const int osel = (h >> 4) & 1;

  u32 ab0[8], ab1[8], ow0[8], ow1[8];
  #pragma unroll
  for (int u = 0; u < 8; ++u) {
    ab0[u] = zfp[zbase + (size_t)u * 384];
    ow0[u] = op[obase + (size_t)u * 192];
  }
  for (int t0 = 0; t0 < 128; t0 += 16) {
    const size_t zb = zbase + (size_t)t0 * 384;
    const size_t ob = obase + (size_t)t0 * 192;
    #pragma unroll
    for (int u = 0; u < 8; ++u) {
      ab1[u] = zfp[zb + (size_t)(u + 8) * 384];
      ow1[u] = op[ob + (size_t)(u + 8) * 192];
    }
    #pragma unroll
    for (int u = 0; u < 8; ++u) {
      c = fmaf(bflo(ab0[u]), c, bfhi(ab0[u]));
      const float o = osel ? bfhi(ow0[u]) : bflo(ow0[u]);
      const float hv = o * c;
      const int t = t0 + u;
      if (WM == 0) {
        const u32 me = (u32)f32_to_bf16_rn(hv);
        const u32 nb = (u32)__shfl_xor((int)me, 1);
        if (!(h & 1)) anext[(size_t)(r0 + t) * 192 + (h >> 1)] = me | (nb << 16);
      } else {
        out[(size_t)((chunk * 128 + t) * 64 + bgRow + b_local) * 384 + h] = hv;
      }
    }
    if (t0 + 16 < 128) {
      #pragma unroll
      for (int u = 0; u < 8; ++u) {
        ab0[u] = zfp[zb + (size_t)(u + 16) * 384];
        ow0[u] = op[ob + (size_t)(u + 16) * 192];
      }
    }
    #pragma unroll
    for (int u = 0; u < 8; ++u) {
      c = fmaf(bflo(ab1[u]), c, bfhi(ab1[u]));
      const float o = osel ? bfhi(ow1[u]) : bflo(ow1[u]);
      const float hv = o * c;
      const int t = t0 + u + 8;
      if (WM == 0) {
        const u32 me = (u32)f32_to_bf16_rn(hv);
        const u32 nb = (u32)__shfl_xor((int)me, 1);
        if (!(h & 1)) anext[(size_t)(r0 + t) * 192 + (h >> 1)] = me | (nb << 16);
      } else {
        out[(size_t)((chunk * 128 + t) * 64 + bgRow + b_local) * 384 + h] = hv;
      }
    }
  }
}

extern "C" void kernel_launch(void* const* d_in, const int* in_sizes, int n_in,
                              void* d_out, int out_size, void* d_ws, size_t ws_size,
                              hipStream_t stream) {
  const float* x  = (const float*)d_in[0];
  const float* Ws = (const float*)d_in[1];
  const float* bs = (const float*)d_in[2];
  float* out = (float*)d_out;

  const size_t wbytes = (size_t)NLAYER * Ncols * Kdim * 2;   // one bf16 plane of W
  int G = 64;
  for (int g = 1; g <= 64; g *= 2) {
    const int Bg_ = BATCH / g;
    const size_t MG_ = (size_t)SEQ * Bg_;
    size_t need = 2 * wbytes
                + MG_ * Kdim * 2              // A plane (bf16)
                + MG_ * 384 * 4               // zf packed u32
                + MG_ * 192 * 4               // o packed u32
                + 2 * (size_t)8 * Bg_ * 384 * 4
                + 16 * 256;
    if (need <= ws_size) { G = g; break; }
  }
  const int Bg = BATCH / G;
  const int MG = SEQ * Bg;
  const int NCHg = Bg * HID;
  const int Mtiles = MG / 128;   // = Bg*8

  char* p = (char*)d_ws;
  auto carve = [&](size_t bytes) -> char* {
    char* r = p; p += (bytes + 255) & ~(size_t)255; return r;
  };
  u16* Whi = (u16*)carve(wbytes);
  u16* Wlo = (u16*)carve(wbytes);
  u32* Ap  = (u32*)carve((size_t)MG * Kdim * 2);
  u32* zf  = (u32*)carve((size_t)MG * 384 * 4);
  u32* ov  = (u32*)carve((size_t)MG * 192 * 4);
  float* cA = (float*)carve((size_t)8 * NCHg * 4);
  float* cB = (float*)carve((size_t)8 * NCHg * 4);

  k_prep_w<<<dim3(Ncols / 64, Kdim / 64, NLAYER), 256, 0, stream>>>(Ws, Whi, Wlo);

  const int scanBlocks = (NCHg + 255) / 256;
  for (int bg = 0; bg < G; ++bg) {
    const int bgRow = bg * Bg;
    const int n8 = MG * (Kdim / 8);
    const int pblocks = (n8 + 255) / 256 < 4096 ? (n8 + 255) / 256 : 4096;
    k_prep_xg<<<pblocks, 256, 0, stream>>>(x, Ap, n8, bgRow);

    for (int layer = 0; layer < NLAYER; ++layer) {
      const u16* wh = Whi + (size_t)layer * Ncols * Kdim;
      const u16* wl = Wlo + (size_t)layer * Ncols * Kdim;
      const float* bias = bs + layer * Ncols;
      k_gemm<<<dim3(9, Mtiles), 256, 0, stream>>>(
          (const u16*)Ap, wh, wl, bias, zf, ov, cA, cB, Mtiles, NCHg);
      if (layer < NLAYER - 1)
        k_scan<0><<<dim3(scanBlocks, 8), 256, 0, stream>>>(
            zf, ov, cA, cB, Ap, out, NCHg, bgRow);
      else
        k_scan<1><<<dim3(scanBlocks, 8), 256, 0, stream>>>(
            zf, ov, cA, cB, Ap, out, NCHg, bgRow);
    }
  }
}

// Round 6
// 868.866 us; speedup vs baseline: 2.5359x; 1.0853x over previous
//
#include <hip/hip_runtime.h>
#include <hip/hip_bf16.h>
#include <stdint.h>

#define SEQ    1024
#define BATCH  64
#define DIN    384
#define HID    384
#define NLAYER 5

constexpr int Ncols = 3 * HID;       // 1152
constexpr int Kdim  = DIN;           // 384

typedef __attribute__((ext_vector_type(8))) __bf16 bf16x8;
typedef __attribute__((ext_vector_type(4))) float  f32x4;
typedef unsigned int u32;
typedef uint16_t u16;

// Wfrag: fragment-major W, uint4 index = ((((layer*9+nt)*4+ws)*6+kt)*8 + c)*64 + lane
//   c = ks*4 + pl*2 + n  (ks: K-half of 64, pl: hi/lo plane, n: n-frag)
//   chunk data: bf16_pl( W[kt*64+ks*32+(lane>>4)*8 + 0..7][j] ), where
//     nt<6 (zf): j = nt*64 + ws*16 + (lane&15) + (n ? 384 : 0)   (z-col / f-col pair)
//     nt>=6 (o): j = 768 + (nt-6)*128 + ws*32 + n*16 + (lane&15)
constexpr int WF_U4_PER_LAYER = 9 * 4 * 6 * 8 * 64;   // 110592 uint4 = 1.77 MB

// ---------- bf16 helpers ----------
__device__ __forceinline__ u16 f32_to_bf16_rn(float x) {
  u32 u = __float_as_uint(x);
  u += 0x7FFFu + ((u >> 16) & 1u);
  return (u16)(u >> 16);
}
__device__ __forceinline__ float bf16_to_f32(u16 h) {
  return __uint_as_float(((u32)h) << 16);
}
__device__ __forceinline__ float bflo(u32 p) { return __uint_as_float(p << 16); }
__device__ __forceinline__ float bfhi(u32 p) { return __uint_as_float(p & 0xFFFF0000u); }
__device__ __forceinline__ u32 packbf(float a, float b) {
  return (u32)f32_to_bf16_rn(a) | ((u32)f32_to_bf16_rn(b) << 16);
}
__device__ __forceinline__ void split2(float x, u16& hi, u16& lo) {
  u16 h = f32_to_bf16_rn(x);
  lo = f32_to_bf16_rn(x - bf16_to_f32(h));
  hi = h;
}

__device__ __forceinline__ void gload_lds16(const void* g, void* l) {
  __builtin_amdgcn_global_load_lds(
      (const __attribute__((address_space(1))) void*)g,
      (__attribute__((address_space(3))) void*)l, 16, 0, 0);
}

// ---------- prep: W (L,K,N) fp32 -> fragment-major bf16 hi/lo chunks ----------
__global__ void k_prep_w(const float* __restrict__ W, uint4* __restrict__ wf) {
  __shared__ float lds[64][130];
  const int nt = blockIdx.x;     // 0..8
  const int kt = blockIdx.y;     // 0..5
  const int layer = blockIdx.z;
  const float* Wl = W + (size_t)layer * Kdim * Ncols + (size_t)kt * 64 * Ncols;
  const int tid = threadIdx.x;
  for (int e = tid; e < 64 * 128; e += 256) {
    const int kl = e >> 7, jj = e & 127;
    int j;
    if (nt < 6) j = (jj < 64) ? (nt * 64 + jj) : (384 + nt * 64 + jj - 64);
    else        j = 768 + (nt - 6) * 128 + jj;
    lds[kl][jj] = Wl[(size_t)kl * Ncols + j];
  }
  __syncthreads();
  #pragma unroll
  for (int i = 0; i < 8; ++i) {
    const int cid = i * 256 + tid;           // 0..2047
    const int ws = cid >> 9;
    const int rem = cid & 511;
    const int c = rem >> 6;
    const int lane = rem & 63;
    const int ks = c >> 2, pl = (c >> 1) & 1, n = c & 1;
    int jj;
    if (nt < 6) jj = ws * 16 + (lane & 15) + (n ? 64 : 0);
    else        jj = ws * 32 + n * 16 + (lane & 15);
    const int kl = ks * 32 + (lane >> 4) * 8;
    u16 h[8];
    #pragma unroll
    for (int t = 0; t < 8; ++t) {
      u16 hi, lo; split2(lds[kl + t][jj], hi, lo);
      h[t] = pl ? lo : hi;
    }
    uint4 o;
    o.x = (u32)h[0] | ((u32)h[1] << 16);
    o.y = (u32)h[2] | ((u32)h[3] << 16);
    o.z = (u32)h[4] | ((u32)h[5] << 16);
    o.w = (u32)h[6] | ((u32)h[7] << 16);
    wf[((((size_t)layer * 9 + nt) * 4 + ws) * 48 + kt * 8 + c) * 64 + lane] = o;
  }
}

// ---------- prep: x (s,b) fp32 -> A (b_local,s) bf16 plane ----------
__global__ void k_prep_xg(const float* __restrict__ x, u32* __restrict__ ap,
                          int n8, int bgRow) {
  int i = blockIdx.x * blockDim.x + threadIdx.x;
  const int stride = gridDim.x * blockDim.x;
  const float4* x4 = (const float4*)x;
  for (; i < n8; i += stride) {
    const int rl = i / 48;
    const int k8 = i - rl * 48;
    const int b_local = rl >> 10, s = rl & 1023;
    const size_t src = (size_t)(s * 64 + bgRow + b_local) * 96 + k8 * 2;
    const float4 v0 = x4[src], v1 = x4[src + 1];
    uint4 o;
    o.x = packbf(v0.x, v0.y); o.y = packbf(v0.z, v0.w);
    o.z = packbf(v1.x, v1.y); o.w = packbf(v1.z, v1.w);
    ((uint4*)ap)[i] = o;
  }
}

// ---------- GEMM: A(LDS,dbuf) x W(frag-major, direct to VGPR) + fused epilogue ----------
// 4 waves, each a 128x32 column strip. Per kt: stage A(t+1), load Wfrag(t+1) to regs,
// compute(t) [16 ds_read + 64 MFMA], barrier (drains loads issued a full tile earlier).
__global__ __launch_bounds__(256, 2) void k_gemm(
    const u16* __restrict__ A,
    const bf16x8* __restrict__ Wf,          // this layer's fragment-major W
    const float* __restrict__ bias,
    u32* __restrict__ zf, u32* __restrict__ ov,
    float* __restrict__ compA, float* __restrict__ compB,
    int Mtiles, int NCHg)
{
  __shared__ char smem[32768];               // A double buffer: 2 x 16 KB

  const int tid  = threadIdx.x;
  // XCD-chunked bijective remap (grid = 9*Mtiles, multiple of 8); n fastest within chunk.
  const int L = blockIdx.y * 9 + blockIdx.x;
  const int q = (9 * Mtiles) >> 3;
  const int nl = (L & 7) * q + (L >> 3);
  const int mt = nl / 9;
  const int nt = nl - mt * 9;
  const int m0 = mt * 128;

  const int wave = tid >> 6, lane = tid & 63;
  const int qv = lane >> 4;
  const int ln = lane & 15;

  // --- accumulators initialized with bias (C-layout: col = lane&15, same for all 4 regs) ---
  float b0i, b1i;
  if (nt < 6) {
    const int hcol = nt * 64 + wave * 16 + ln;
    b0i = bias[hcol];            // Z bias
    b1i = bias[384 + hcol];      // F bias
  } else {
    const int hb = (nt - 6) * 128 + wave * 32 + ln;
    b0i = bias[768 + hb];
    b1i = bias[768 + hb + 16];
  }
  f32x4 acc[8][2];
  #pragma unroll
  for (int m = 0; m < 8; ++m) {
    acc[m][0] = f32x4{b0i, b0i, b0i, b0i};
    acc[m][1] = f32x4{b1i, b1i, b1i, b1i};
  }

  // --- per-lane constant addresses ---
  const int sr   = tid >> 3;     // 0..31
  const int sseg = tid & 7;
  // A ds_read base per ks (swizzle part depends only on lane)
  u32 abase[2];
  #pragma unroll
  for (int ks = 0; ks < 2; ++ks)
    abase[ks] = (u32)(ln * 128 + (((ks * 4 + qv) ^ (ln & 7)) * 16));
  // W fragment base for this (nt, wave)
  const bf16x8* wbase = Wf + ((size_t)(nt * 4 + wave) * 48) * 64 + lane;

  bf16x8 Wcur[8], Wnxt[8];

  // stage A(kt) into buf p
  auto stageA = [&](int kt, int p) {
    #pragma unroll
    for (int i = 0; i < 4; ++i) {
      const int r = i * 32 + sr;
      const int seg = sseg ^ (r & 7);
      const size_t ea = (size_t)(m0 + r) * Kdim + kt * 64 + seg * 8;
      gload_lds16(A + ea, smem + p * 16384 + r * 128 + sseg * 16);
    }
  };

  stageA(0, 0);
  #pragma unroll
  for (int c = 0; c < 8; ++c) Wcur[c] = wbase[c * 64];
  __syncthreads();

  #pragma unroll
  for (int kt = 0; kt < 6; ++kt) {
    const int p = kt & 1;
    if (kt < 5) {
      stageA(kt + 1, p ^ 1);
      #pragma unroll
      for (int c = 0; c < 8; ++c) Wnxt[c] = wbase[((kt + 1) * 8 + c) * 64];
    }
    #pragma unroll
    for (int ks = 0; ks < 2; ++ks) {
      bf16x8 fA[8];
      #pragma unroll
      for (int m = 0; m < 8; ++m)
        fA[m] = *(const bf16x8*)(smem + p * 16384 + m * 2048 + abase[ks]);
      #pragma unroll
      for (int m = 0; m < 8; ++m) {
        acc[m][0] = __builtin_amdgcn_mfma_f32_16x16x32_bf16(fA[m], Wcur[ks * 4 + 0], acc[m][0], 0, 0, 0);
        acc[m][1] = __builtin_amdgcn_mfma_f32_16x16x32_bf16(fA[m], Wcur[ks * 4 + 1], acc[m][1], 0, 0, 0);
        acc[m][0] = __builtin_amdgcn_mfma_f32_16x16x32_bf16(fA[m], Wcur[ks * 4 + 2], acc[m][0], 0, 0, 0);
        acc[m][1] = __builtin_amdgcn_mfma_f32_16x16x32_bf16(fA[m], Wcur[ks * 4 + 3], acc[m][1], 0, 0, 0);
      }
    }
    if (kt < 5) {
      __syncthreads();
      #pragma unroll
      for (int c = 0; c < 8; ++c) Wcur[c] = Wnxt[c];
    }
  }

  // ---------- epilogue ----------
  if (nt < 6) {
    const int hcol = nt * 64 + wave * 16 + ln;
    float Arun = 1.f, Brun = 0.f;
    #pragma unroll
    for (int m = 0; m < 8; ++m) {
      float Aseg = 1.f, Bseg = 0.f;
      #pragma unroll
      for (int r = 0; r < 4; ++r) {
        const float vz = acc[m][0][r];            // bias already included
        const float vf = acc[m][1][r];
        const float z = fmaf(2.f, __builtin_amdgcn_rcpf(1.f + __expf(-2.f * vz)), -1.f);
        const float f = __builtin_amdgcn_rcpf(1.f + __expf(-vf));
        const float av = 1.f - f;
        const float bb = f * z;
        const int row = m * 16 + qv * 4 + r;
        zf[(size_t)(m0 + row) * 384 + hcol] = packbf(av, bb);
        Bseg = fmaf(av, Bseg, bb);
        Aseg *= av;
      }
      {
        const float Ao = __shfl_xor(Aseg, 16), Bo = __shfl_xor(Bseg, 16);
        const bool late = qv & 1;
        const float Ae = late ? Ao : Aseg, Be = late ? Bo : Bseg;
        const float Al = late ? Aseg : Ao, Bl = late ? Bseg : Bo;
        Aseg = Al * Ae; Bseg = fmaf(Al, Be, Bl);
      }
      {
        const float Ao = __shfl_xor(Aseg, 32), Bo = __shfl_xor(Bseg, 32);
        const bool late = (qv >> 1) & 1;
        const float Ae = late ? Ao : Aseg, Be = late ? Bo : Bseg;
        const float Al = late ? Aseg : Ao, Bl = late ? Bseg : Bo;
        Aseg = Al * Ae; Bseg = fmaf(Al, Be, Bl);
      }
      Brun = fmaf(Aseg, Brun, Bseg);
      Arun *= Aseg;
    }
    if (qv == 0) {
      const int b_local = mt >> 3, chunk = mt & 7;
      const int chg = b_local * 384 + hcol;
      compA[chunk * NCHg + chg] = Arun;
      compB[chunk * NCHg + chg] = Brun;
    }
  } else {
    const int hb = (nt - 6) * 128 + wave * 32 + ln;
    const int pos = ((hb >> 5) << 4) + (hb & 15);
    #pragma unroll
    for (int m = 0; m < 8; ++m)
      #pragma unroll
      for (int r = 0; r < 4; ++r) {
        const float s0 = __builtin_amdgcn_rcpf(1.f + __expf(-acc[m][0][r]));
        const float s1 = __builtin_amdgcn_rcpf(1.f + __expf(-acc[m][1][r]));
        const int row = m * 16 + qv * 4 + r;
        ov[(size_t)(m0 + row) * 192 + pos] = packbf(s0, s1);
      }
  }
}

// ---------- scan: fold chunk prefix, apply recurrence, write h ----------
template<int WM>  // 0: write bf16 A plane (next layer input)  1: write fp32 out (s,b)
__global__ void k_scan(const u32* __restrict__ zfp, const u32* __restrict__ op,
                       const float* __restrict__ compA, const float* __restrict__ compB,
                       u32* __restrict__ anext, float* __restrict__ out,
                       int NCHg, int bgRow)
{
  const int ch = blockIdx.x * blockDim.x + threadIdx.x;
  if (ch >= NCHg) return;
  const int chunk = blockIdx.y;
  const int b_local = ch / 384;
  const int h = ch - b_local * 384;
  float c = 0.f;
  for (int q = 0; q < chunk; ++q)
    c = fmaf(compA[q * NCHg + ch], c, compB[q * NCHg + ch]);

  const int r0 = b_local * 1024 + chunk * 128;
  const size_t zbase = (size_t)r0 * 384 + h;
  const size_t obase = (size_t)r0 * 192 + (((h >> 5) << 4) + (h & 15));
  const int osel = (h >> 4) & 1;

  u32 ab0[8], ab1[8], ow0[8], ow1[8];
  #pragma unroll
  for (int u = 0; u < 8; ++u) {
    ab0[u] = zfp[zbase + (size_t)u * 384];
    ow0[u] = op[obase + (size_t)u * 192];
  }
  for (int t0 = 0; t0 < 128; t0 += 16) {
    const size_t zb = zbase + (size_t)t0 * 384;
    const size_t ob = obase + (size_t)t0 * 192;
    #pragma unroll
    for (int u = 0; u < 8; ++u) {
      ab1[u] = zfp[zb + (size_t)(u + 8) * 384];
      ow1[u] = op[ob + (size_t)(u + 8) * 192];
    }
    #pragma unroll
    for (int u = 0; u < 8; ++u) {
      c = fmaf(bflo(ab0[u]), c, bfhi(ab0[u]));
      const float o = osel ? bfhi(ow0[u]) : bflo(ow0[u]);
      const float hv = o * c;
      const int t = t0 + u;
      if (WM == 0) {
        const u32 me = (u32)f32_to_bf16_rn(hv);
        const u32 nb = (u32)__shfl_xor((int)me, 1);
        if (!(h & 1)) anext[(size_t)(r0 + t) * 192 + (h >> 1)] = me | (nb << 16);
      } else {
        out[(size_t)((chunk * 128 + t) * 64 + bgRow + b_local) * 384 + h] = hv;
      }
    }
    if (t0 + 16 < 128) {
      #pragma unroll
      for (int u = 0; u < 8; ++u) {
        ab0[u] = zfp[zb + (size_t)(u + 16) * 384];
        ow0[u] = op[ob + (size_t)(u + 16) * 192];
      }
    }
    #pragma unroll
    for (int u = 0; u < 8; ++u) {
      c = fmaf(bflo(ab1[u]), c, bfhi(ab1[u]));
      const float o = osel ? bfhi(ow1[u]) : bflo(ow1[u]);
      const float hv = o * c;
      const int t = t0 + u + 8;
      if (WM == 0) {
        const u32 me = (u32)f32_to_bf16_rn(hv);
        const u32 nb = (u32)__shfl_xor((int)me, 1);
        if (!(h & 1)) anext[(size_t)(r0 + t) * 192 + (h >> 1)] = me | (nb << 16);
      } else {
        out[(size_t)((chunk * 128 + t) * 64 + bgRow + b_local) * 384 + h] = hv;
      }
    }
  }
}

extern "C" void kernel_launch(void* const* d_in, const int* in_sizes, int n_in,
                              void* d_out, int out_size, void* d_ws, size_t ws_size,
                              hipStream_t stream) {
  const float* x  = (const float*)d_in[0];
  const float* Ws = (const float*)d_in[1];
  const float* bs = (const float*)d_in[2];
  float* out = (float*)d_out;

  const size_t wfbytes = (size_t)NLAYER * WF_U4_PER_LAYER * 16;   // 8.85 MB
  int G = 64;
  for (int g = 1; g <= 64; g *= 2) {
    const int Bg_ = BATCH / g;
    const size_t MG_ = (size_t)SEQ * Bg_;
    size_t need = wfbytes
                + MG_ * Kdim * 2              // A plane (bf16)
                + MG_ * 384 * 4               // zf packed u32
                + MG_ * 192 * 4               // o packed u32
                + 2 * (size_t)8 * Bg_ * 384 * 4
                + 16 * 256;
    if (need <= ws_size) { G = g; break; }
  }
  const int Bg = BATCH / G;
  const int MG = SEQ * Bg;
  const int NCHg = Bg * HID;
  const int Mtiles = MG / 128;   // = Bg*8

  char* p = (char*)d_ws;
  auto carve = [&](size_t bytes) -> char* {
    char* r = p; p += (bytes + 255) & ~(size_t)255; return r;
  };
  uint4* Wf = (uint4*)carve(wfbytes);
  u32* Ap  = (u32*)carve((size_t)MG * Kdim * 2);
  u32* zf  = (u32*)carve((size_t)MG * 384 * 4);
  u32* ov  = (u32*)carve((size_t)MG * 192 * 4);
  float* cA = (float*)carve((size_t)8 * NCHg * 4);
  float* cB = (float*)carve((size_t)8 * NCHg * 4);

  k_prep_w<<<dim3(9, 6, NLAYER), 256, 0, stream>>>(Ws, Wf);

  const int scanBlocks = (NCHg + 255) / 256;
  for (int bg = 0; bg < G; ++bg) {
    const int bgRow = bg * Bg;
    const int n8 = MG * (Kdim / 8);
    const int pblocks = (n8 + 255) / 256 < 4096 ? (n8 + 255) / 256 : 4096;
    k_prep_xg<<<pblocks, 256, 0, stream>>>(x, Ap, n8, bgRow);

    for (int layer = 0; layer < NLAYER; ++layer) {
      const bf16x8* wl = (const bf16x8*)(Wf + (size_t)layer * WF_U4_PER_LAYER);
      const float* bias = bs + layer * Ncols;
      k_gemm<<<dim3(9, Mtiles), 256, 0, stream>>>(
          (const u16*)Ap, wl, bias, zf, ov, cA, cB, Mtiles, NCHg);
      if (layer < NLAYER - 1)
        k_scan<0><<<dim3(scanBlocks, 8), 256, 0, stream>>>(
            zf, ov, cA, cB, Ap, out, NCHg, bgRow);
      else
        k_scan<1><<<dim3(scanBlocks, 8), 256, 0, stream>>>(
            zf, ov, cA, cB, Ap, out, NCHg, bgRow);
    }
  }
}

// Round 7
// 844.606 us; speedup vs baseline: 2.6087x; 1.0287x over previous
//
#include <hip/hip_runtime.h>
#include <hip/hip_bf16.h>
#include <stdint.h>

#define SEQ    1024
#define BATCH  64
#define DIN    384
#define HID    384
#define NLAYER 5

constexpr int Ncols = 3 * HID;       // 1152
constexpr int Kdim  = 384;

typedef __attribute__((ext_vector_type(8))) __bf16 bf16x8;
typedef __attribute__((ext_vector_type(4))) float  f32x4;
typedef unsigned int u32;
typedef uint16_t u16;

// Wfrag: fragment-major W, uint4 index = ((((layer*9+nt)*4+ws)*6+kt)*8 + c)*64 + lane
//   c = ks*4 + pl*2 + n  (ks: K-half of 64, pl: hi/lo plane, n: n-frag)
constexpr int WF_U4_PER_LAYER = 9 * 4 * 6 * 8 * 64;   // 110592 uint4 = 1.77 MB

// ---------- bf16 helpers ----------
__device__ __forceinline__ u16 f32_to_bf16_rn(float x) {
  u32 u = __float_as_uint(x);
  u += 0x7FFFu + ((u >> 16) & 1u);
  return (u16)(u >> 16);
}
__device__ __forceinline__ float bf16_to_f32(u16 h) {
  return __uint_as_float(((u32)h) << 16);
}
__device__ __forceinline__ float bflo(u32 p) { return __uint_as_float(p << 16); }
__device__ __forceinline__ float bfhi(u32 p) { return __uint_as_float(p & 0xFFFF0000u); }
__device__ __forceinline__ u32 packbf(float a, float b) {
  return (u32)f32_to_bf16_rn(a) | ((u32)f32_to_bf16_rn(b) << 16);
}
__device__ __forceinline__ void split2(float x, u16& hi, u16& lo) {
  u16 h = f32_to_bf16_rn(x);
  lo = f32_to_bf16_rn(x - bf16_to_f32(h));
  hi = h;
}

__device__ __forceinline__ void gload_lds16(const void* g, void* l) {
  __builtin_amdgcn_global_load_lds(
      (const __attribute__((address_space(1))) void*)g,
      (__attribute__((address_space(3))) void*)l, 16, 0, 0);
}

// ---------- prep: W (L,K,N) fp32 -> fragment-major bf16 hi/lo chunks ----------
__global__ void k_prep_w(const float* __restrict__ W, uint4* __restrict__ wf) {
  __shared__ float lds[64][130];
  const int nt = blockIdx.x;     // 0..8
  const int kt = blockIdx.y;     // 0..5
  const int layer = blockIdx.z;
  const float* Wl = W + (size_t)layer * Kdim * Ncols + (size_t)kt * 64 * Ncols;
  const int tid = threadIdx.x;
  for (int e = tid; e < 64 * 128; e += 256) {
    const int kl = e >> 7, jj = e & 127;
    int j;
    if (nt < 6) j = (jj < 64) ? (nt * 64 + jj) : (384 + nt * 64 + jj - 64);
    else        j = 768 + (nt - 6) * 128 + jj;
    lds[kl][jj] = Wl[(size_t)kl * Ncols + j];
  }
  __syncthreads();
  #pragma unroll
  for (int i = 0; i < 8; ++i) {
    const int cid = i * 256 + tid;           // 0..2047
    const int ws = cid >> 9;
    const int rem = cid & 511;
    const int c = rem >> 6;
    const int lane = rem & 63;
    const int ks = c >> 2, pl = (c >> 1) & 1, n = c & 1;
    int jj;
    if (nt < 6) jj = ws * 16 + (lane & 15) + (n ? 64 : 0);
    else        jj = ws * 32 + n * 16 + (lane & 15);
    const int kl = ks * 32 + (lane >> 4) * 8;
    u16 h[8];
    #pragma unroll
    for (int t = 0; t < 8; ++t) {
      u16 hi, lo; split2(lds[kl + t][jj], hi, lo);
      h[t] = pl ? lo : hi;
    }
    uint4 o;
    o.x = (u32)h[0] | ((u32)h[1] << 16);
    o.y = (u32)h[2] | ((u32)h[3] << 16);
    o.z = (u32)h[4] | ((u32)h[5] << 16);
    o.w = (u32)h[6] | ((u32)h[7] << 16);
    wf[((((size_t)layer * 9 + nt) * 4 + ws) * 48 + kt * 8 + c) * 64 + lane] = o;
  }
}

// ---------- prep: x (s,b) fp32 -> A (b_local,s) bf16 plane ----------
__global__ void k_prep_xg(const float* __restrict__ x, u32* __restrict__ ap,
                          int n8, int bgRow) {
  int i = blockIdx.x * blockDim.x + threadIdx.x;
  const int stride = gridDim.x * blockDim.x;
  const float4* x4 = (const float4*)x;
  for (; i < n8; i += stride) {
    const int rl = i / 48;
    const int k8 = i - rl * 48;
    const int b_local = rl >> 10, s = rl & 1023;
    const size_t src = (size_t)(s * 64 + bgRow + b_local) * 96 + k8 * 2;
    const float4 v0 = x4[src], v1 = x4[src + 1];
    uint4 o;
    o.x = packbf(v0.x, v0.y); o.y = packbf(v0.z, v0.w);
    o.z = packbf(v1.x, v1.y); o.w = packbf(v1.z, v1.w);
    ((uint4*)ap)[i] = o;
  }
}

// ---------- GEMM: A(LDS, 3-stage pipeline, counted vmcnt) x W(frag-major to VGPR) ----------
// 4 waves, each a 128x32 column strip. Ledger (4 A-loads/stage, 8 W-loads/kt), issue order:
//   st0 st1 W0 | st2 W1 | st3 W2 | st4 W3 | st5 W4 | W5
// before barrier(t) need stage(t) landed -> vmcnt(N), N = ops newer than stage(t):
//   t=0:12  t=1..4:20  t=5:16
__global__ __launch_bounds__(256, 3) void k_gemm(
    const u16* __restrict__ A,
    const bf16x8* __restrict__ Wf,
    const float* __restrict__ bias,
    u32* __restrict__ zf, u32* __restrict__ ov,
    float* __restrict__ compA, float* __restrict__ compB,
    int Mtiles, int NCHg)
{
  __shared__ char smem[49152];               // A triple buffer: 3 x 16 KB

  const int tid  = threadIdx.x;
  const int L = blockIdx.y * 9 + blockIdx.x;
  const int q = (9 * Mtiles) >> 3;
  const int nl = (L & 7) * q + (L >> 3);
  const int mt = nl / 9;
  const int nt = nl - mt * 9;
  const int m0 = mt * 128;

  const int wave = tid >> 6, lane = tid & 63;
  const int qv = lane >> 4;
  const int ln = lane & 15;

  float b0i, b1i;
  if (nt < 6) {
    const int hcol = nt * 64 + wave * 16 + ln;
    b0i = bias[hcol];
    b1i = bias[384 + hcol];
  } else {
    const int hb = (nt - 6) * 128 + wave * 32 + ln;
    b0i = bias[768 + hb];
    b1i = bias[768 + hb + 16];
  }
  f32x4 acc[8][2];
  #pragma unroll
  for (int m = 0; m < 8; ++m) {
    acc[m][0] = f32x4{b0i, b0i, b0i, b0i};
    acc[m][1] = f32x4{b1i, b1i, b1i, b1i};
  }

  const int sr   = tid >> 3;
  const int sseg = tid & 7;
  u32 abase[2];
  #pragma unroll
  for (int ks = 0; ks < 2; ++ks)
    abase[ks] = (u32)(ln * 128 + (((ks * 4 + qv) ^ (ln & 7)) * 16));
  const bf16x8* wbase = Wf + ((size_t)(nt * 4 + wave) * 48) * 64 + lane;

  bf16x8 W[2][8];

#define STAGE(KT, P)                                                          \
  {                                                                           \
    _Pragma("unroll")                                                         \
    for (int i = 0; i < 4; ++i) {                                             \
      const int r = i * 32 + sr;                                              \
      const int seg = sseg ^ (r & 7);                                         \
      const size_t ea = (size_t)(m0 + r) * Kdim + (KT) * 64 + seg * 8;        \
      gload_lds16(A + ea, smem + (P) * 16384 + r * 128 + sseg * 16);          \
    }                                                                         \
  }

#define LOADW(KT, WP)                                                         \
  {                                                                           \
    _Pragma("unroll")                                                         \
    for (int c = 0; c < 8; ++c) W[WP][c] = wbase[((KT) * 8 + c) * 64];        \
  }

#define COMPUTE(P, WP)                                                        \
  {                                                                           \
    __builtin_amdgcn_s_setprio(1);                                            \
    _Pragma("unroll")                                                         \
    for (int ks = 0; ks < 2; ++ks) {                                          \
      bf16x8 fA[8];                                                           \
      _Pragma("unroll")                                                       \
      for (int m = 0; m < 8; ++m)                                             \
        fA[m] = *(const bf16x8*)(smem + (P) * 16384 + m * 2048 + abase[ks]);  \
      _Pragma("unroll")                                                       \
      for (int m = 0; m < 8; ++m) {                                           \
        acc[m][0] = __builtin_amdgcn_mfma_f32_16x16x32_bf16(fA[m], W[WP][ks * 4 + 0], acc[m][0], 0, 0, 0); \
        acc[m][1] = __builtin_amdgcn_mfma_f32_16x16x32_bf16(fA[m], W[WP][ks * 4 + 1], acc[m][1], 0, 0, 0); \
        acc[m][0] = __builtin_amdgcn_mfma_f32_16x16x32_bf16(fA[m], W[WP][ks * 4 + 2], acc[m][0], 0, 0, 0); \
        acc[m][1] = __builtin_amdgcn_mfma_f32_16x16x32_bf16(fA[m], W[WP][ks * 4 + 3], acc[m][1], 0, 0, 0); \
      }                                                                       \
    }                                                                         \
    __builtin_amdgcn_s_setprio(0);                                            \
  }

#define WAITBAR(N)                                                            \
  asm volatile("s_waitcnt vmcnt(" #N ")" ::: "memory");                       \
  asm volatile("s_barrier" ::: "memory");

  // prologue
  STAGE(0, 0); STAGE(1, 1); LOADW(0, 0);
  // kt = 0
  WAITBAR(12); STAGE(2, 2); LOADW(1, 1); COMPUTE(0, 0);
  // kt = 1
  WAITBAR(20); STAGE(3, 0); LOADW(2, 0); COMPUTE(1, 1);
  // kt = 2
  WAITBAR(20); STAGE(4, 1); LOADW(3, 1); COMPUTE(2, 0);
  // kt = 3
  WAITBAR(20); STAGE(5, 2); LOADW(4, 0); COMPUTE(0, 1);
  // kt = 4
  WAITBAR(20); LOADW(5, 1); COMPUTE(1, 0);
  // kt = 5
  WAITBAR(16); COMPUTE(2, 1);

#undef STAGE
#undef LOADW
#undef COMPUTE
#undef WAITBAR

  // ---------- epilogue ----------
  if (nt < 6) {
    const int hcol = nt * 64 + wave * 16 + ln;
    float Arun = 1.f, Brun = 0.f;
    #pragma unroll
    for (int m = 0; m < 8; ++m) {
      float Aseg = 1.f, Bseg = 0.f;
      #pragma unroll
      for (int r = 0; r < 4; ++r) {
        const float vz = acc[m][0][r];
        const float vf = acc[m][1][r];
        const float z = fmaf(2.f, __builtin_amdgcn_rcpf(1.f + __expf(-2.f * vz)), -1.f);
        const float f = __builtin_amdgcn_rcpf(1.f + __expf(-vf));
        const float av = 1.f - f;
        const float bb = f * z;
        const int row = m * 16 + qv * 4 + r;
        zf[(size_t)(m0 + row) * 384 + hcol] = packbf(av, bb);
        Bseg = fmaf(av, Bseg, bb);
        Aseg *= av;
      }
      {
        const float Ao = __shfl_xor(Aseg, 16), Bo = __shfl_xor(Bseg, 16);
        const bool late = qv & 1;
        const float Ae = late ? Ao : Aseg, Be = late ? Bo : Bseg;
        const float Al = late ? Aseg : Ao, Bl = late ? Bseg : Bo;
        Aseg = Al * Ae; Bseg = fmaf(Al, Be, Bl);
      }
      {
        const float Ao = __shfl_xor(Aseg, 32), Bo = __shfl_xor(Bseg, 32);
        const bool late = (qv >> 1) & 1;
        const float Ae = late ? Ao : Aseg, Be = late ? Bo : Bseg;
        const float Al = late ? Aseg : Ao, Bl = late ? Bseg : Bo;
        Aseg = Al * Ae; Bseg = fmaf(Al, Be, Bl);
      }
      Brun = fmaf(Aseg, Brun, Bseg);
      Arun *= Aseg;
    }
    if (qv == 0) {
      const int b_local = mt >> 3, chunk = mt & 7;
      const int chg = b_local * 384 + hcol;
      compA[chunk * NCHg + chg] = Arun;
      compB[chunk * NCHg + chg] = Brun;
    }
  } else {
    const int hb = (nt - 6) * 128 + wave * 32 + ln;
    const int pos = ((hb >> 5) << 4) + (hb & 15);
    #pragma unroll
    for (int m = 0; m < 8; ++m)
      #pragma unroll
      for (int r = 0; r < 4; ++r) {
        const float s0 = __builtin_amdgcn_rcpf(1.f + __expf(-acc[m][0][r]));
        const float s1 = __builtin_amdgcn_rcpf(1.f + __expf(-acc[m][1][r]));
        const int row = m * 16 + qv * 4 + r;
        ov[(size_t)(m0 + row) * 192 + pos] = packbf(s0, s1);
      }
  }
}

// ---------- scan: fold chunk prefix, apply recurrence, write h ----------
template<int WM>  // 0: write bf16 A plane (next layer input)  1: write fp32 out (s,b)
__global__ void k_scan(const u32* __restrict__ zfp, const u32* __restrict__ op,
                       const float* __restrict__ compA, const float* __restrict__ compB,
                       u32* __restrict__ anext, float* __restrict__ out,
                       int NCHg, int bgRow)
{
  const int ch = blockIdx.x * blockDim.x + threadIdx.x;
  if (ch >= NCHg) return;
  const int chunk = blockIdx.y;
  const int b_local = ch / 384;
  const int h = ch - b_local * 384;
  float c = 0.f;
  for (int q = 0; q < chunk; ++q)
    c = fmaf(compA[q * NCHg + ch], c, compB[q * NCHg + ch]);

  const int r0 = b_local * 1024 + chunk * 128;
  const size_t zbase = (size_t)r0 * 384 + h;
  const size_t obase = (size_t)r0 * 192 + (((h >> 5) << 4) + (h & 15));
  const int osel = (h >> 4) & 1;

  u32 ab0[8], ab1[8], ow0[8], ow1[8];
  #pragma unroll
  for (int u = 0; u < 8; ++u) {
    ab0[u] = zfp[zbase + (size_t)u * 384];
    ow0[u] = op[obase + (size_t)u * 192];
  }
  for (int t0 = 0; t0 < 128; t0 += 16) {
    const size_t zb = zbase + (size_t)t0 * 384;
    const size_t ob = obase + (size_t)t0 * 192;
    #pragma unroll
    for (int u = 0; u < 8; ++u) {
      ab1[u] = zfp[zb + (size_t)(u + 8) * 384];
      ow1[u] = op[ob + (size_t)(u + 8) * 192];
    }
    #pragma unroll
    for (int u = 0; u < 8; ++u) {
      c = fmaf(bflo(ab0[u]), c, bfhi(ab0[u]));
      const float o = osel ? bfhi(ow0[u]) : bflo(ow0[u]);
      const float hv = o * c;
      const int t = t0 + u;
      if (WM == 0) {
        const u32 me = (u32)f32_to_bf16_rn(hv);
        const u32 nb = (u32)__shfl_xor((int)me, 1);
        if (!(h & 1)) anext[(size_t)(r0 + t) * 192 + (h >> 1)] = me | (nb << 16);
      } else {
        out[(size_t)((chunk * 128 + t) * 64 + bgRow + b_local) * 384 + h] = hv;
      }
    }
    if (t0 + 16 < 128) {
      #pragma unroll
      for (int u = 0; u < 8; ++u) {
        ab0[u] = zfp[zb + (size_t)(u + 16) * 384];
        ow0[u] = op[ob + (size_t)(u + 16) * 192];
      }
    }
    #pragma unroll
    for (int u = 0; u < 8; ++u) {
      c = fmaf(bflo(ab1[u]), c, bfhi(ab1[u]));
      const float o = osel ? bfhi(ow1[u]) : bflo(ow1[u]);
      const float hv = o * c;
      const int t = t0 + u + 8;
      if (WM == 0) {
        const u32 me = (u32)f32_to_bf16_rn(hv);
        const u32 nb = (u32)__shfl_xor((int)me, 1);
        if (!(h & 1)) anext[(size_t)(r0 + t) * 192 + (h >> 1)] = me | (nb << 16);
      } else {
        out[(size_t)((chunk * 128 + t) * 64 + bgRow + b_local) * 384 + h] = hv;
      }
    }
  }
}

extern "C" void kernel_launch(void* const* d_in, const int* in_sizes, int n_in,
                              void* d_out, int out_size, void* d_ws, size_t ws_size,
                              hipStream_t stream) {
  const float* x  = (const float*)d_in[0];
  const float* Ws = (const float*)d_in[1];
  const float* bs = (const float*)d_in[2];
  float* out = (float*)d_out;

  const size_t wfbytes = (size_t)NLAYER * WF_U4_PER_LAYER * 16;   // 8.85 MB
  int G = 64;
  for (int g = 1; g <= 64; g *= 2) {
    const int Bg_ = BATCH / g;
    const size_t MG_ = (size_t)SEQ * Bg_;
    size_t need = wfbytes
                + MG_ * Kdim * 2
                + MG_ * 384 * 4
                + MG_ * 192 * 4
                + 2 * (size_t)8 * Bg_ * 384 * 4
                + 16 * 256;
    if (need <= ws_size) { G = g; break; }
  }
  const int Bg = BATCH / G;
  const int MG = SEQ * Bg;
  const int NCHg = Bg * HID;
  const int Mtiles = MG / 128;

  char* p = (char*)d_ws;
  auto carve = [&](size_t bytes) -> char* {
    char* r = p; p += (bytes + 255) & ~(size_t)255; return r;
  };
  uint4* Wf = (uint4*)carve(wfbytes);
  u32* Ap  = (u32*)carve((size_t)MG * Kdim * 2);
  u32* zf  = (u32*)carve((size_t)MG * 384 * 4);
  u32* ov  = (u32*)carve((size_t)MG * 192 * 4);
  float* cA = (float*)carve((size_t)8 * NCHg * 4);
  float* cB = (float*)carve((size_t)8 * NCHg * 4);

  k_prep_w<<<dim3(9, 6, NLAYER), 256, 0, stream>>>(Ws, Wf);

  const int scanBlocks = (NCHg + 255) / 256;
  for (int bg = 0; bg < G; ++bg) {
    const int bgRow = bg * Bg;
    const int n8 = MG * (Kdim / 8);
    const int pblocks = (n8 + 255) / 256 < 4096 ? (n8 + 255) / 256 : 4096;
    k_prep_xg<<<pblocks, 256, 0, stream>>>(x, Ap, n8, bgRow);

    for (int layer = 0; layer < NLAYER; ++layer) {
      const bf16x8* wl = (const bf16x8*)(Wf + (size_t)layer * WF_U4_PER_LAYER);
      const float* bias = bs + layer * Ncols;
      k_gemm<<<dim3(9, Mtiles), 256, 0, stream>>>(
          (const u16*)Ap, wl, bias, zf, ov, cA, cB, Mtiles, NCHg);
      if (layer < NLAYER - 1)
        k_scan<0><<<dim3(scanBlocks, 8), 256, 0, stream>>>(
            zf, ov, cA, cB, Ap, out, NCHg, bgRow);
      else
        k_scan<1><<<dim3(scanBlocks, 8), 256, 0, stream>>>(
            zf, ov, cA, cB, Ap, out, NCHg, bgRow);
    }
  }
}